// Round 1
// baseline (291.850 us; speedup 1.0000x reference)
//
#include <hip/hip_runtime.h>
#include <hip/hip_bf16.h>
#include <string.h>

#define B_ 32
#define LQ_ 256
#define H_ 256
#define NH_ 8
#define LK_ 512
#define N_ 8192
#define DH_ 32

typedef float floatx4 __attribute__((ext_vector_type(4)));
typedef short shortx8 __attribute__((ext_vector_type(8)));
typedef short shortx4 __attribute__((ext_vector_type(4)));

__device__ __forceinline__ short f2b(float f) {
    __hip_bfloat16 h = __float2bfloat16(f);
    short s;
    __builtin_memcpy(&s, &h, 2);
    return s;
}
__device__ __forceinline__ float b2f(short s) {
    unsigned u = ((unsigned)(unsigned short)s) << 16;
    float f;
    __builtin_memcpy(&f, &u, 4);
    return f;
}

#define LOG2E 1.44269504088896f

// ================= PHASE 1: zero ∥ prep_w ∥ gather =================
__global__ __launch_bounds__(256) void phase1(
    const float* __restrict__ graph, const float* __restrict__ rel,
    const int* __restrict__ src, const int* __restrict__ dst,
    const int* __restrict__ eb, const float* __restrict__ pad_mask,
    const float* __restrict__ Wq, const float* __restrict__ Wk,
    const float* __restrict__ Wv, const float* __restrict__ Wo,
    const float* __restrict__ W1, const float* __restrict__ W2,
    short* __restrict__ WT, short* __restrict__ key_pad,
    short* __restrict__ val_pad, float* __restrict__ zbase, int E) {
    const int bid = blockIdx.x, tid = threadIdx.x;
    if (bid < 8192) {
        int row = bid * 2 + (tid >> 7);
        int t = tid & 127;
        int b = row >> 9, p = row & 511;
        bool valid = pad_mask[row] > 0.5f;
        size_t krow = (size_t)row * 512;
        size_t vrow = (size_t)row * 256;
        int kc = t * 4, vc = t * 2;
        if (valid) {
            int lo = 0, hi = E;
            while (lo < hi) { int mid = (lo + hi) >> 1; if (eb[mid] < b) lo = mid + 1; else hi = mid; }
            int e = lo + p;
            int s = src[e], d = dst[e];
            const float* sp = (kc < 256) ? (graph + (size_t)s * 256 + kc)
                                         : (rel + (size_t)e * 256 + (kc - 256));
            float4 k4 = *(const float4*)sp;
            key_pad[krow + kc + 0] = f2b(k4.x);
            key_pad[krow + kc + 1] = f2b(k4.y);
            key_pad[krow + kc + 2] = f2b(k4.z);
            key_pad[krow + kc + 3] = f2b(k4.w);
            float2 v2 = *(const float2*)(graph + (size_t)d * 256 + vc);
            val_pad[vrow + vc + 0] = f2b(v2.x);
            val_pad[vrow + vc + 1] = f2b(v2.y);
        } else {
            *(long long*)&key_pad[krow + kc] = 0;
            *(int*)&val_pad[vrow + vc] = 0;
        }
    } else if (bid < 9984) {
        int i = (bid - 8192) * 256 + tid;
        const float* s;
        int K, loc;
        if (i < 65536) { s = Wq; K = 256; loc = i; }
        else if (i < 196608) { s = Wk; K = 512; loc = i - 65536; }
        else {
            int m = (i - 196608) >> 16;
            loc = (i - 196608) & 65535;
            K = 256;
            s = (m == 0) ? Wv : (m == 1) ? Wo : (m == 2) ? W1 : W2;
        }
        int n = loc / K, k = loc - n * K;
        WT[i] = f2b(s[(size_t)k * 256 + n]);
    } else {
        long long n = (long long)N_ * H_ + N_;
        for (long long i = (long long)(bid - 9984) * 256 + tid; i < n; i += 512 * 256)
            zbase[i] = 0.f;
    }
}

// ================= PHASE 2: QKV GEMMs (+ transposed Vt, Qt) =================
// id<512: Qb = query@Wq      (normal,  C[q][c])
// 512..1535: Kb = key_pad@Wk (normal,  C[k][c])
// 1536..2559: Vt[b][c][k] = (val_pad@Wv)^T  (A=WTv rows=channels, B=val_pad rows=tokens)
// 2560..3071: Qt[b][c][q] = (query@Wq)^T    (A=WTq, B=query f32)
__global__ __launch_bounds__(256) void phase2_gemm(
    const float* __restrict__ query, const short* __restrict__ key_pad,
    const short* __restrict__ val_pad, const short* __restrict__ WT,
    const float* __restrict__ bq, const float* __restrict__ bk,
    const float* __restrict__ bv,
    short* __restrict__ Qb, short* __restrict__ Kb,
    short* __restrict__ Vt, short* __restrict__ Qt) {
    __shared__ short As[64][40];
    __shared__ short Bs[64][40];
    const int tid = threadIdx.x;
    const int id = blockIdx.x;
    const float* Af = nullptr; const short* Ab = nullptr;
    const float* Bf = nullptr; const short* Bb = nullptr;
    const float* bias; short* C;
    size_t cbase; int cstride, K; bool biasM;
    if (id < 512) {
        int rb = id >> 2, cb = id & 3;
        Af = query + (size_t)(rb * 64) * 256; K = 256;
        Bb = WT + (size_t)(cb * 64) * 256;
        bias = bq + cb * 64; biasM = false;
        C = Qb; cbase = (size_t)(rb * 64) * 256 + cb * 64; cstride = 256;
    } else if (id < 1536) {
        int t = id - 512; int rb = t >> 2, cb = t & 3;
        Ab = key_pad + (size_t)(rb * 64) * 512; K = 512;
        Bb = WT + 65536 + (size_t)(cb * 64) * 512;
        bias = bk + cb * 64; biasM = false;
        C = Kb; cbase = (size_t)(rb * 64) * 256 + cb * 64; cstride = 256;
    } else if (id < 2560) {
        int t = id - 1536; int b = t >> 5, ct = (t >> 3) & 3, kt = t & 7;
        Ab = WT + 196608 + (size_t)(ct * 64) * 256; K = 256;
        Bb = val_pad + ((size_t)(b * 512 + kt * 64)) * 256;
        bias = bv + ct * 64; biasM = true;
        C = Vt; cbase = ((size_t)(b * 256 + ct * 64)) * 512 + kt * 64; cstride = 512;
    } else {
        int t = id - 2560; int b = t >> 4, ct = (t >> 2) & 3, qt = t & 3;
        Ab = WT + (size_t)(ct * 64) * 256; K = 256;
        Bf = query + ((size_t)(b * 256 + qt * 64)) * 256;
        bias = bq + ct * 64; biasM = true;
        C = Qt; cbase = ((size_t)(b * 256 + ct * 64)) * 256 + qt * 64; cstride = 256;
    }
    const int wv = tid >> 6, lane = tid & 63;
    const int mw = (wv & 1) * 32, nw = (wv >> 1) * 32;
    const int lm = lane & 15, quad = lane >> 4;

    floatx4 acc[2][2] = {{{0.f, 0.f, 0.f, 0.f}, {0.f, 0.f, 0.f, 0.f}},
                         {{0.f, 0.f, 0.f, 0.f}, {0.f, 0.f, 0.f, 0.f}}};

    for (int kc = 0; kc < K; kc += 32) {
        int r = tid >> 2, kq = (tid & 3) * 8;
        if (Af) {
            const float* ap = Af + (size_t)r * K + kc + kq;
            float4 a1 = *(const float4*)ap, a2 = *(const float4*)(ap + 4);
            As[r][kq + 0] = f2b(a1.x); As[r][kq + 1] = f2b(a1.y);
            As[r][kq + 2] = f2b(a1.z); As[r][kq + 3] = f2b(a1.w);
            As[r][kq + 4] = f2b(a2.x); As[r][kq + 5] = f2b(a2.y);
            As[r][kq + 6] = f2b(a2.z); As[r][kq + 7] = f2b(a2.w);
        } else {
            *(shortx8*)&As[r][kq] = *(const shortx8*)(Ab + (size_t)r * K + kc + kq);
        }
        if (Bf) {
            const float* bp = Bf + (size_t)r * K + kc + kq;
            float4 b1 = *(const float4*)bp, b2 = *(const float4*)(bp + 4);
            Bs[r][kq + 0] = f2b(b1.x); Bs[r][kq + 1] = f2b(b1.y);
            Bs[r][kq + 2] = f2b(b1.z); Bs[r][kq + 3] = f2b(b1.w);
            Bs[r][kq + 4] = f2b(b2.x); Bs[r][kq + 5] = f2b(b2.y);
            Bs[r][kq + 6] = f2b(b2.z); Bs[r][kq + 7] = f2b(b2.w);
        } else {
            *(shortx8*)&Bs[r][kq] = *(const shortx8*)(Bb + (size_t)r * K + kc + kq);
        }
        __syncthreads();
        shortx8 a0 = *(const shortx8*)&As[mw + lm][quad * 8];
        shortx8 a1 = *(const shortx8*)&As[mw + 16 + lm][quad * 8];
        shortx8 b0 = *(const shortx8*)&Bs[nw + lm][quad * 8];
        shortx8 b1 = *(const shortx8*)&Bs[nw + 16 + lm][quad * 8];
        acc[0][0] = __builtin_amdgcn_mfma_f32_16x16x32_bf16(a0, b0, acc[0][0], 0, 0, 0);
        acc[0][1] = __builtin_amdgcn_mfma_f32_16x16x32_bf16(a0, b1, acc[0][1], 0, 0, 0);
        acc[1][0] = __builtin_amdgcn_mfma_f32_16x16x32_bf16(a1, b0, acc[1][0], 0, 0, 0);
        acc[1][1] = __builtin_amdgcn_mfma_f32_16x16x32_bf16(a1, b1, acc[1][1], 0, 0, 0);
        __syncthreads();
    }
#pragma unroll
    for (int i = 0; i < 2; i++) {
#pragma unroll
        for (int j = 0; j < 2; j++) {
            int gn = nw + j * 16 + lm;
#pragma unroll
            for (int r = 0; r < 4; r++) {
                int gm = mw + i * 16 + quad * 4 + r;
                float bvv = biasM ? bias[gm] : bias[gn];
                C[cbase + (size_t)gm * cstride + gn] = f2b(acc[i][j][r] + bvv);
            }
        }
    }
}

// ================= PHASE 3: both attention passes =================
// Swapped QK^T (A=K/Q-chunk, B=Q/K-window from global): lane holds 4 consecutive
// contraction-axis entries for fixed output row -> packed b64 P-store into SB4[q][k].
// Flipped PV (A=Vt/Qt from LDS, B=P): both operands k-contiguous, no transposes.
// SB4 rows are wave-private: no barrier between QK and PV.
__global__ __launch_bounds__(256, 4) void phase3_attn(
    const short* __restrict__ Qm, const short* __restrict__ Km,
    const short* __restrict__ Vt, const short* __restrict__ Qt,
    const float* __restrict__ pad_mask, const float* __restrict__ ext,
    short* __restrict__ qctx, short* __restrict__ vctx) {
    __shared__ short SB2[128][40];   // pass1: K chunk [k][d]; pass2: Q chunk [q][d]
    __shared__ short SB3[32][136];   // pass1: Vt slice [d][k]; pass2: Qt slice [d][q]
    __shared__ short SB4[64][136];   // P bf16: pass1 [q][k]; pass2 [k][q]
    const int tid = threadIdx.x;
    const int wv = tid >> 6, lane = tid & 63;
    const int lm = lane & 15, quad = lane >> 4;
    const float scale2 = 0.17677669529663687f * LOG2E;
    const int id = blockIdx.x;

    if (id < 1024) {
        const int q0 = (id & 3) * 64, h = (id >> 2) & 7, b = id >> 5;
        // Q B-frag direct from global (one 16B load, held in VGPRs)
        shortx8 bqf = *(const shortx8*)(
            Qm + ((size_t)(b * 256 + q0 + wv * 16 + lm)) * 256 + h * 32 + quad * 8);
        floatx4 oacc0 = {0.f, 0.f, 0.f, 0.f}, oacc1 = {0.f, 0.f, 0.f, 0.f};
        float psum = 0.f;
        for (int c = 0; c < 4; c++) {
            const int kbase = c * 128;
            {   // K chunk -> SB2 [128][32]
                int r = tid >> 1, dq = (tid & 1) * 16;
                const short* kp = Km + ((size_t)(b * 512 + kbase + r)) * 256 + h * 32 + dq;
                *(shortx8*)&SB2[r][dq] = *(const shortx8*)kp;
                *(shortx8*)&SB2[r][dq + 8] = *(const shortx8*)(kp + 8);
            }
            {   // Vt slice -> SB3 [32][128] (vector loads, no transpose)
                int r = tid >> 3, kq = (tid & 7) * 16;
                const short* vp = Vt + ((size_t)(b * 256 + h * 32 + r)) * 512 + kbase + kq;
                *(shortx8*)&SB3[r][kq] = *(const shortx8*)vp;
                *(shortx8*)&SB3[r][kq + 8] = *(const shortx8*)(vp + 8);
            }
            __syncthreads();
            const floatx4* pmp = (const floatx4*)(pad_mask + b * 512 + kbase);
#pragma unroll
            for (int nt = 0; nt < 8; nt++) {
                shortx8 ak = *(const shortx8*)&SB2[nt * 16 + lm][quad * 8];
                floatx4 s = {0.f, 0.f, 0.f, 0.f};
                s = __builtin_amdgcn_mfma_f32_16x16x32_bf16(ak, bqf, s, 0, 0, 0);
                // S^T[k][q]: row k = nt*16+quad*4+r, col q = wv*16+lm
                floatx4 pm = pmp[nt * 4 + quad];
                shortx4 p4;
#pragma unroll
                for (int r = 0; r < 4; r++) {
                    float e = __builtin_amdgcn_exp2f(
                        s[r] * scale2 + (1.0f - pm[r]) * (-10000.0f * LOG2E));
                    psum += e;
                    p4[r] = f2b(e);
                }
                *(long long*)&SB4[wv * 16 + lm][nt * 16 + quad * 4] = *(long long*)&p4;
            }
            // PV: A = Vt rows (d), B = P rows (q, own wave) -> C[d][q]
#pragma unroll
            for (int kk = 0; kk < 4; kk++) {
                shortx8 pb = *(const shortx8*)&SB4[wv * 16 + lm][kk * 32 + quad * 8];
                shortx8 a0 = *(const shortx8*)&SB3[lm][kk * 32 + quad * 8];
                shortx8 a1 = *(const shortx8*)&SB3[16 + lm][kk * 32 + quad * 8];
                oacc0 = __builtin_amdgcn_mfma_f32_16x16x32_bf16(a0, pb, oacc0, 0, 0, 0);
                oacc1 = __builtin_amdgcn_mfma_f32_16x16x32_bf16(a1, pb, oacc1, 0, 0, 0);
            }
            __syncthreads();
        }
        psum += __shfl_xor(psum, 16, 64);
        psum += __shfl_xor(psum, 32, 64);
        float inv = 1.0f / psum;
        int q = q0 + wv * 16 + lm;
        short* op = qctx + ((size_t)(b * 256 + q)) * 256 + h * 32;
        shortx4 o0, o1;
#pragma unroll
        for (int r = 0; r < 4; r++) {
            o0[r] = f2b(oacc0[r] * inv);
            o1[r] = f2b(oacc1[r] * inv);
        }
        *(long long*)(op + quad * 4) = *(long long*)&o0;
        *(long long*)(op + 16 + quad * 4) = *(long long*)&o1;
    } else {
        const int id2 = id - 1024;
        const int k0 = (id2 & 7) * 64, h = (id2 >> 3) & 7, b = id2 >> 6;
        shortx8 bkf = *(const shortx8*)(
            Km + ((size_t)(b * 512 + k0 + wv * 16 + lm)) * 256 + h * 32 + quad * 8);
        floatx4 oacc0 = {0.f, 0.f, 0.f, 0.f}, oacc1 = {0.f, 0.f, 0.f, 0.f};
        float psum = 0.f;
        for (int c = 0; c < 2; c++) {
            const int qbase = c * 128;
            {   // Q chunk -> SB2 [128][32]
                int r = tid >> 1, dq = (tid & 1) * 16;
                const short* qp = Qm + ((size_t)(b * 256 + qbase + r)) * 256 + h * 32 + dq;
                *(shortx8*)&SB2[r][dq] = *(const shortx8*)qp;
                *(shortx8*)&SB2[r][dq + 8] = *(const shortx8*)(qp + 8);
            }
            {   // Qt slice -> SB3 [32][128]
                int r = tid >> 3, kq = (tid & 7) * 16;
                const short* tp = Qt + ((size_t)(b * 256 + h * 32 + r)) * 256 + qbase + kq;
                *(shortx8*)&SB3[r][kq] = *(const shortx8*)tp;
                *(shortx8*)&SB3[r][kq + 8] = *(const shortx8*)(tp + 8);
            }
            __syncthreads();
            const floatx4* emp = (const floatx4*)(ext + b * 256 + qbase);
#pragma unroll
            for (int nt = 0; nt < 8; nt++) {
                shortx8 aq = *(const shortx8*)&SB2[nt * 16 + lm][quad * 8];
                floatx4 s = {0.f, 0.f, 0.f, 0.f};
                s = __builtin_amdgcn_mfma_f32_16x16x32_bf16(aq, bkf, s, 0, 0, 0);
                // S[q][k]: row q = nt*16+quad*4+r, col k = wv*16+lm
                floatx4 em = emp[nt * 4 + quad];
                shortx4 p4;
#pragma unroll
                for (int r = 0; r < 4; r++) {
                    float e = __builtin_amdgcn_exp2f(s[r] * scale2 + em[r] * LOG2E);
                    psum += e;
                    p4[r] = f2b(e);
                }
                *(long long*)&SB4[wv * 16 + lm][nt * 16 + quad * 4] = *(long long*)&p4;
            }
#pragma unroll
            for (int kk = 0; kk < 4; kk++) {
                shortx8 pb = *(const shortx8*)&SB4[wv * 16 + lm][kk * 32 + quad * 8];
                shortx8 a0 = *(const shortx8*)&SB3[lm][kk * 32 + quad * 8];
                shortx8 a1 = *(const shortx8*)&SB3[16 + lm][kk * 32 + quad * 8];
                oacc0 = __builtin_amdgcn_mfma_f32_16x16x32_bf16(a0, pb, oacc0, 0, 0, 0);
                oacc1 = __builtin_amdgcn_mfma_f32_16x16x32_bf16(a1, pb, oacc1, 0, 0, 0);
            }
            __syncthreads();
        }
        psum += __shfl_xor(psum, 16, 64);
        psum += __shfl_xor(psum, 32, 64);
        float inv = 1.0f / psum;
        int k = k0 + wv * 16 + lm;
        short* op = vctx + ((size_t)(b * 512 + k)) * 256 + h * 32;
        shortx4 o0, o1;
#pragma unroll
        for (int r = 0; r < 4; r++) {
            o0[r] = f2b(oacc0[r] * inv);
            o1[r] = f2b(oacc1[r] * inv);
        }
        *(long long*)(op + quad * 4) = *(long long*)&o0;
        *(long long*)(op + 16 + quad * 4) = *(long long*)&o1;
    }
}

// ================= PHASE 4a: tail GEMMs (64x64 tiles, f32 out) =================
__global__ __launch_bounds__(256) void phase4a_gemm(
    const short* __restrict__ qctx, const short* __restrict__ vctx,
    const short* __restrict__ val_pad, const short* __restrict__ WTo,
    const short* __restrict__ WT1, const short* __restrict__ WT2,
    float* __restrict__ obuf, float* __restrict__ tbuf) {
    __shared__ short As1[64][40];
    __shared__ short As2[64][40];
    __shared__ short Bs1[64][40];
    __shared__ short Bs2[64][40];
    const int tid = threadIdx.x;
    const int id = blockIdx.x;
    const bool is_out = id < 512;
    int t = is_out ? id : id - 512;
    const int row0 = (t >> 2) * 64, col0 = (t & 3) * 64;
    const int wv = tid >> 6, lane = tid & 63;
    const int mw = (wv & 1) * 32, nw = (wv >> 1) * 32;
    const int lm = lane & 15, quad = lane >> 4;

    floatx4 acc[2][2] = {{{0.f, 0.f, 0.f, 0.f}, {0.f, 0.f, 0.f, 0.f}},
                         {{0.f, 0.f, 0.f, 0.f}, {0.f, 0.f, 0.f, 0.f}}};

    for (int kc = 0; kc < 256; kc += 32) {
        int r = tid >> 2, kq = (tid & 3) * 8;
        if (is_out) {
            *(shortx8*)&As1[r][kq] =
                *(const shortx8*)(qctx + (size_t)(row0 + r) * 256 + kc + kq);
            *(shortx8*)&Bs1[r][kq] =
                *(const shortx8*)(WTo + (size_t)(col0 + r) * 256 + kc + kq);
        } else {
            *(shortx8*)&As1[r][kq] =
                *(const shortx8*)(vctx + (size_t)(row0 + r) * 256 + kc + kq);
            *(shortx8*)&As2[r][kq] =
                *(const shortx8*)(val_pad + (size_t)(row0 + r) * 256 + kc + kq);
            *(shortx8*)&Bs1[r][kq] =
                *(const shortx8*)(WT1 + (size_t)(col0 + r) * 256 + kc + kq);
            *(shortx8*)&Bs2[r][kq] =
                *(const shortx8*)(WT2 + (size_t)(col0 + r) * 256 + kc + kq);
        }
        __syncthreads();
        shortx8 a0 = *(const shortx8*)&As1[mw + lm][quad * 8];
        shortx8 a1 = *(const shortx8*)&As1[mw + 16 + lm][quad * 8];
        shortx8 b0 = *(const shortx8*)&Bs1[nw + lm][quad * 8];
        shortx8 b1 = *(const shortx8*)&Bs1[nw + 16 + lm][quad * 8];
        acc[0][0] = __builtin_amdgcn_mfma_f32_16x16x32_bf16(a0, b0, acc[0][0], 0, 0, 0);
        acc[0][1] = __builtin_amdgcn_mfma_f32_16x16x32_bf16(a0, b1, acc[0][1], 0, 0, 0);
        acc[1][0] = __builtin_amdgcn_mfma_f32_16x16x32_bf16(a1, b0, acc[1][0], 0, 0, 0);
        acc[1][1] = __builtin_amdgcn_mfma_f32_16x16x32_bf16(a1, b1, acc[1][1], 0, 0, 0);
        if (!is_out) {
            shortx8 c0 = *(const shortx8*)&As2[mw + lm][quad * 8];
            shortx8 c1 = *(const shortx8*)&As2[mw + 16 + lm][quad * 8];
            shortx8 d0 = *(const shortx8*)&Bs2[nw + lm][quad * 8];
            shortx8 d1 = *(const shortx8*)&Bs2[nw + 16 + lm][quad * 8];
            acc[0][0] = __builtin_amdgcn_mfma_f32_16x16x32_bf16(c0, d0, acc[0][0], 0, 0, 0);
            acc[0][1] = __builtin_amdgcn_mfma_f32_16x16x32_bf16(c0, d1, acc[0][1], 0, 0, 0);
            acc[1][0] = __builtin_amdgcn_mfma_f32_16x16x32_bf16(c1, d0, acc[1][0], 0, 0, 0);
            acc[1][1] = __builtin_amdgcn_mfma_f32_16x16x32_bf16(c1, d1, acc[1][1], 0, 0, 0);
        }
        __syncthreads();
    }
    float* C = is_out ? obuf : tbuf;
#pragma unroll
    for (int i = 0; i < 2; i++) {
#pragma unroll
        for (int j = 0; j < 2; j++) {
            int gn = col0 + nw + j * 16 + lm;
#pragma unroll
            for (int r = 0; r < 4; r++) {
                int gm = row0 + mw + i * 16 + quad * 4 + r;
                C[(size_t)gm * 256 + gn] = acc[i][j][r];
            }
        }
    }
}

// ================= PHASE 4b: LN epilogues + scatter (1 row / block) =================
__global__ __launch_bounds__(256) void phase4b_ln(
    const float* __restrict__ obuf, const float* __restrict__ bo,
    const float* __restrict__ query, const float* __restrict__ g1,
    const float* __restrict__ be1, float* __restrict__ out_q,
    const float* __restrict__ tbuf, const short* __restrict__ vctx,
    const short* __restrict__ val_pad, const float* __restrict__ b1_,
    const float* __restrict__ b2_, const float* __restrict__ g2,
    const float* __restrict__ be2, const float* __restrict__ pad_mask,
    const int* __restrict__ eb, const int* __restrict__ dst,
    float* __restrict__ sums, int* __restrict__ icnts, int E) {
    __shared__ float red[8];
    const int c = threadIdx.x;
    const int wave = c >> 6;
    if (blockIdx.x < 8192) {
        int row = blockIdx.x;
        long long idx = (long long)row * H_ + c;
        float x = obuf[idx] + bo[c] + query[idx];
        float t = x;
        for (int off = 32; off > 0; off >>= 1) t += __shfl_down(t, off, 64);
        if ((c & 63) == 0) red[wave] = t;
        __syncthreads();
        float mean = (red[0] + red[1] + red[2] + red[3]) * (1.0f / H_);
        float dv = x - mean;
        float v = dv * dv;
        for (int off = 32; off > 0; off >>= 1) v += __shfl_down(v, off, 64);
        if ((c & 63) == 0) red[4 + wave] = v;
        __syncthreads();
        float var = (red[4] + red[5] + red[6] + red[7]) * (1.0f / H_);
        out_q[idx] = dv * rsqrtf(var + 1e-12f) * g1[c] + be1[c];
    } else {
        int row = blockIdx.x - 8192;
        bool valid = pad_mask[row] > 0.5f;
        if (!valid) return;
        long long idx = (long long)row * H_ + c;
        float th = 1.0f / (1.0f + __expf(-(tbuf[idx] + b1_[c] + b2_[c])));
        float x = th * b2f(vctx[idx]) + (1.0f - th) * b2f(val_pad[idx]);
        float t = x;
        for (int off = 32; off > 0; off >>= 1) t += __shfl_down(t, off, 64);
        if ((c & 63) == 0) red[wave] = t;
        __syncthreads();
        float mean = (red[0] + red[1] + red[2] + red[3]) * (1.0f / H_);
        float dv = x - mean;
        float v = dv * dv;
        for (int off = 32; off > 0; off >>= 1) v += __shfl_down(v, off, 64);
        if ((c & 63) == 0) red[4 + wave] = v;
        __syncthreads();
        float var = (red[4] + red[5] + red[6] + red[7]) * (1.0f / H_);
        float y = dv * rsqrtf(var + 1e-12f) * g2[c] + be2[c];
        int b = row >> 9;
        int lo = 0, hi = E;
        while (lo < hi) { int mid = (lo + hi) >> 1; if (eb[mid] < b) lo = mid + 1; else hi = mid; }
        int d = dst[lo + (row & 511)];
        atomicAdd(&sums[(size_t)d * 256 + c], y);
        if (c == 0) atomicAdd(&icnts[d], 1);
    }
}

// ================= PHASE 5: finalize =================
__global__ __launch_bounds__(256) void finalize_graph(
    const float* __restrict__ sums, const int* __restrict__ icnts,
    const float* __restrict__ graph, float* __restrict__ out_g) {
    int n = blockIdx.x, c = threadIdx.x;
    long long idx = (long long)n * H_ + c;
    int cnt = icnts[n];
    out_g[idx] = (cnt > 0) ? sums[idx] / (float)cnt : graph[idx];
}

extern "C" void kernel_launch(void* const* d_in, const int* in_sizes, int n_in,
                              void* d_out, int out_size, void* d_ws, size_t ws_size,
                              hipStream_t stream) {
    const float* ext_mask = (const float*)d_in[0];
    const float* query    = (const float*)d_in[1];
    const float* rel      = (const float*)d_in[2];
    const float* graph    = (const float*)d_in[3];
    const int*  src      = (const int*)d_in[4];
    const int*  dst      = (const int*)d_in[5];
    const int*  eb       = (const int*)d_in[6];
    const int*  ep       = (const int*)d_in[7];
    const float* pad_mask = (const float*)d_in[8];
    const float* Wq = (const float*)d_in[9];  const float* bq = (const float*)d_in[10];
    const float* Wk = (const float*)d_in[11]; const float* bk = (const float*)d_in[12];
    const float* Wv = (const float*)d_in[13]; const float* bv = (const float*)d_in[14];
    const float* Wo = (const float*)d_in[15]; const float* bo = (const float*)d_in[16];
    const float* g1 = (const float*)d_in[17]; const float* be1 = (const float*)d_in[18];
    const float* W1 = (const float*)d_in[19]; const float* b1 = (const float*)d_in[20];
    const float* W2 = (const float*)d_in[21]; const float* b2 = (const float*)d_in[22];
    const float* g2 = (const float*)d_in[23]; const float* be2 = (const float*)d_in[24];
    const int E = in_sizes[2] / H_;
    (void)ep;

    float* out_g = (float*)d_out;
    float* out_q = (float*)d_out + (size_t)N_ * H_;

    short* sp = (short*)d_ws;
    short* key_pad = sp; sp += (size_t)B_ * LK_ * 2 * H_;
    short* val_pad = sp; sp += (size_t)B_ * LK_ * H_;
    short* Qb      = sp; sp += (size_t)B_ * LQ_ * H_;
    short* Kb      = sp; sp += (size_t)B_ * LK_ * H_;
    short* Vt      = sp; sp += (size_t)B_ * H_ * LK_;   // [b][c][k]
    short* Qt      = sp; sp += (size_t)B_ * H_ * LQ_;   // [b][c][q]
    short* qctx    = sp; sp += (size_t)B_ * LQ_ * H_;
    short* vctx    = sp; sp += (size_t)B_ * LK_ * H_;
    short* WT      = sp; sp += 458752;
    short* WTo = WT + 262144;
    short* WT1 = WT + 327680;
    short* WT2 = WT + 393216;
    float* fp = (float*)(((size_t)sp + 15) & ~(size_t)15);
    float* sums = fp; fp += (size_t)N_ * H_;
    int*   icnts = (int*)fp; fp += N_;
    float* obuf = fp; fp += (size_t)B_ * LQ_ * H_;   // f32 [8192,256]
    float* tbuf = fp; fp += (size_t)B_ * LK_ * H_;   // f32 [16384,256]

    phase1<<<10496, 256, 0, stream>>>(graph, rel, src, dst, eb, pad_mask,
                                      Wq, Wk, Wv, Wo, W1, W2,
                                      WT, key_pad, val_pad, sums, E);
    phase2_gemm<<<3072, 256, 0, stream>>>(query, key_pad, val_pad, WT,
                                          bq, bk, bv, Qb, Kb, Vt, Qt);
    phase3_attn<<<3072, 256, 0, stream>>>(Qb, Kb, Vt, Qt, pad_mask, ext_mask,
                                          qctx, vctx);
    phase4a_gemm<<<1536, 256, 0, stream>>>(qctx, vctx, val_pad, WTo, WT1, WT2,
                                           obuf, tbuf);
    phase4b_ln<<<24576, 256, 0, stream>>>(obuf, bo, query, g1, be1, out_q,
                                          tbuf, vctx, val_pad, b1, b2, g2, be2,
                                          pad_mask, eb, dst, sums, icnts, E);
    finalize_graph<<<N_, 256, 0, stream>>>(sums, icnts, graph, out_g);
}

// Round 2
// 282.700 us; speedup vs baseline: 1.0324x; 1.0324x over previous
//
#include <hip/hip_runtime.h>
#include <hip/hip_bf16.h>
#include <string.h>

#define B_ 32
#define LQ_ 256
#define H_ 256
#define NH_ 8
#define LK_ 512
#define N_ 8192
#define DH_ 32

typedef float floatx4 __attribute__((ext_vector_type(4)));
typedef short shortx8 __attribute__((ext_vector_type(8)));
typedef short shortx4 __attribute__((ext_vector_type(4)));

__device__ __forceinline__ short f2b(float f) {
    __hip_bfloat16 h = __float2bfloat16(f);
    short s;
    __builtin_memcpy(&s, &h, 2);
    return s;
}
__device__ __forceinline__ float b2f(short s) {
    unsigned u = ((unsigned)(unsigned short)s) << 16;
    float f;
    __builtin_memcpy(&f, &u, 4);
    return f;
}

#define LOG2E 1.44269504088896f

// ================= PHASE 1: zero ∥ prep_w ∥ gather =================
__global__ __launch_bounds__(256) void phase1(
    const float* __restrict__ graph, const float* __restrict__ rel,
    const int* __restrict__ src, const int* __restrict__ dst,
    const int* __restrict__ eb, const float* __restrict__ pad_mask,
    const float* __restrict__ Wq, const float* __restrict__ Wk,
    const float* __restrict__ Wv, const float* __restrict__ Wo,
    const float* __restrict__ W1, const float* __restrict__ W2,
    short* __restrict__ WT, short* __restrict__ key_pad,
    short* __restrict__ val_pad, float* __restrict__ zbase, int E) {
    const int bid = blockIdx.x, tid = threadIdx.x;
    if (bid < 8192) {
        int row = bid * 2 + (tid >> 7);
        int t = tid & 127;
        int b = row >> 9, p = row & 511;
        bool valid = pad_mask[row] > 0.5f;
        size_t krow = (size_t)row * 512;
        size_t vrow = (size_t)row * 256;
        int kc = t * 4, vc = t * 2;
        if (valid) {
            int lo = 0, hi = E;
            while (lo < hi) { int mid = (lo + hi) >> 1; if (eb[mid] < b) lo = mid + 1; else hi = mid; }
            int e = lo + p;
            int s = src[e], d = dst[e];
            const float* sp = (kc < 256) ? (graph + (size_t)s * 256 + kc)
                                         : (rel + (size_t)e * 256 + (kc - 256));
            float4 k4 = *(const float4*)sp;
            key_pad[krow + kc + 0] = f2b(k4.x);
            key_pad[krow + kc + 1] = f2b(k4.y);
            key_pad[krow + kc + 2] = f2b(k4.z);
            key_pad[krow + kc + 3] = f2b(k4.w);
            float2 v2 = *(const float2*)(graph + (size_t)d * 256 + vc);
            val_pad[vrow + vc + 0] = f2b(v2.x);
            val_pad[vrow + vc + 1] = f2b(v2.y);
        } else {
            *(long long*)&key_pad[krow + kc] = 0;
            *(int*)&val_pad[vrow + vc] = 0;
        }
    } else if (bid < 9984) {
        int i = (bid - 8192) * 256 + tid;
        const float* s;
        int K, loc;
        if (i < 65536) { s = Wq; K = 256; loc = i; }
        else if (i < 196608) { s = Wk; K = 512; loc = i - 65536; }
        else {
            int m = (i - 196608) >> 16;
            loc = (i - 196608) & 65535;
            K = 256;
            s = (m == 0) ? Wv : (m == 1) ? Wo : (m == 2) ? W1 : W2;
        }
        int n = loc / K, k = loc - n * K;
        WT[i] = f2b(s[(size_t)k * 256 + n]);
    } else {
        long long n = (long long)N_ * H_ + N_;
        for (long long i = (long long)(bid - 9984) * 256 + tid; i < n; i += 512 * 256)
            zbase[i] = 0.f;
    }
}

// ================= PHASE 2: QKV GEMMs (+ transposed Vt, Qt) =================
__global__ __launch_bounds__(256) void phase2_gemm(
    const float* __restrict__ query, const short* __restrict__ key_pad,
    const short* __restrict__ val_pad, const short* __restrict__ WT,
    const float* __restrict__ bq, const float* __restrict__ bk,
    const float* __restrict__ bv,
    short* __restrict__ Qb, short* __restrict__ Kb,
    short* __restrict__ Vt, short* __restrict__ Qt) {
    __shared__ short As[64][40];
    __shared__ short Bs[64][40];
    const int tid = threadIdx.x;
    const int id = blockIdx.x;
    const float* Af = nullptr; const short* Ab = nullptr;
    const float* Bf = nullptr; const short* Bb = nullptr;
    const float* bias; short* C;
    size_t cbase; int cstride, K; bool biasM;
    if (id < 512) {
        int rb = id >> 2, cb = id & 3;
        Af = query + (size_t)(rb * 64) * 256; K = 256;
        Bb = WT + (size_t)(cb * 64) * 256;
        bias = bq + cb * 64; biasM = false;
        C = Qb; cbase = (size_t)(rb * 64) * 256 + cb * 64; cstride = 256;
    } else if (id < 1536) {
        int t = id - 512; int rb = t >> 2, cb = t & 3;
        Ab = key_pad + (size_t)(rb * 64) * 512; K = 512;
        Bb = WT + 65536 + (size_t)(cb * 64) * 512;
        bias = bk + cb * 64; biasM = false;
        C = Kb; cbase = (size_t)(rb * 64) * 256 + cb * 64; cstride = 256;
    } else if (id < 2560) {
        int t = id - 1536; int b = t >> 5, ct = (t >> 3) & 3, kt = t & 7;
        Ab = WT + 196608 + (size_t)(ct * 64) * 256; K = 256;
        Bb = val_pad + ((size_t)(b * 512 + kt * 64)) * 256;
        bias = bv + ct * 64; biasM = true;
        C = Vt; cbase = ((size_t)(b * 256 + ct * 64)) * 512 + kt * 64; cstride = 512;
    } else {
        int t = id - 2560; int b = t >> 4, ct = (t >> 2) & 3, qt = t & 3;
        Ab = WT + (size_t)(ct * 64) * 256; K = 256;
        Bf = query + ((size_t)(b * 256 + qt * 64)) * 256;
        bias = bq + ct * 64; biasM = true;
        C = Qt; cbase = ((size_t)(b * 256 + ct * 64)) * 256 + qt * 64; cstride = 256;
    }
    const int wv = tid >> 6, lane = tid & 63;
    const int mw = (wv & 1) * 32, nw = (wv >> 1) * 32;
    const int lm = lane & 15, quad = lane >> 4;

    floatx4 acc[2][2] = {{{0.f, 0.f, 0.f, 0.f}, {0.f, 0.f, 0.f, 0.f}},
                         {{0.f, 0.f, 0.f, 0.f}, {0.f, 0.f, 0.f, 0.f}}};

    for (int kc = 0; kc < K; kc += 32) {
        int r = tid >> 2, kq = (tid & 3) * 8;
        if (Af) {
            const float* ap = Af + (size_t)r * K + kc + kq;
            float4 a1 = *(const float4*)ap, a2 = *(const float4*)(ap + 4);
            As[r][kq + 0] = f2b(a1.x); As[r][kq + 1] = f2b(a1.y);
            As[r][kq + 2] = f2b(a1.z); As[r][kq + 3] = f2b(a1.w);
            As[r][kq + 4] = f2b(a2.x); As[r][kq + 5] = f2b(a2.y);
            As[r][kq + 6] = f2b(a2.z); As[r][kq + 7] = f2b(a2.w);
        } else {
            *(shortx8*)&As[r][kq] = *(const shortx8*)(Ab + (size_t)r * K + kc + kq);
        }
        if (Bf) {
            const float* bp = Bf + (size_t)r * K + kc + kq;
            float4 b1 = *(const float4*)bp, b2 = *(const float4*)(bp + 4);
            Bs[r][kq + 0] = f2b(b1.x); Bs[r][kq + 1] = f2b(b1.y);
            Bs[r][kq + 2] = f2b(b1.z); Bs[r][kq + 3] = f2b(b1.w);
            Bs[r][kq + 4] = f2b(b2.x); Bs[r][kq + 5] = f2b(b2.y);
            Bs[r][kq + 6] = f2b(b2.z); Bs[r][kq + 7] = f2b(b2.w);
        } else {
            *(shortx8*)&Bs[r][kq] = *(const shortx8*)(Bb + (size_t)r * K + kc + kq);
        }
        __syncthreads();
        shortx8 a0 = *(const shortx8*)&As[mw + lm][quad * 8];
        shortx8 a1 = *(const shortx8*)&As[mw + 16 + lm][quad * 8];
        shortx8 b0 = *(const shortx8*)&Bs[nw + lm][quad * 8];
        shortx8 b1 = *(const shortx8*)&Bs[nw + 16 + lm][quad * 8];
        acc[0][0] = __builtin_amdgcn_mfma_f32_16x16x32_bf16(a0, b0, acc[0][0], 0, 0, 0);
        acc[0][1] = __builtin_amdgcn_mfma_f32_16x16x32_bf16(a0, b1, acc[0][1], 0, 0, 0);
        acc[1][0] = __builtin_amdgcn_mfma_f32_16x16x32_bf16(a1, b0, acc[1][0], 0, 0, 0);
        acc[1][1] = __builtin_amdgcn_mfma_f32_16x16x32_bf16(a1, b1, acc[1][1], 0, 0, 0);
        __syncthreads();
    }
#pragma unroll
    for (int i = 0; i < 2; i++) {
#pragma unroll
        for (int j = 0; j < 2; j++) {
            int gn = nw + j * 16 + lm;
#pragma unroll
            for (int r = 0; r < 4; r++) {
                int gm = mw + i * 16 + quad * 4 + r;
                float bvv = biasM ? bias[gm] : bias[gn];
                C[cbase + (size_t)gm * cstride + gn] = f2b(acc[i][j][r] + bvv);
            }
        }
    }
}

// ================= PHASE 3: attention, (b,h)-blocked for exact reuse =========
// pass1 (id<256): block=(b,h), 8 waves x 32 q rows. Swapped QK^T C[k][q]
//   (A=K chunk from LDS, B=Q frags in regs), wave-private P[q][k] in LDS,
//   PV C[d][q] (A=Vt slice from LDS, B=P). All LDS ops are b64/b128.
// pass2 (id>=256): block=(b,h,k-half), 8 waves x 32 k rows, symmetric.
__global__ __launch_bounds__(512, 4) void phase3_attn(
    const short* __restrict__ Qm, const short* __restrict__ Km,
    const short* __restrict__ Vt, const short* __restrict__ Qt,
    const float* __restrict__ pad_mask, const float* __restrict__ ext,
    short* __restrict__ qctx, short* __restrict__ vctx) {
    __shared__ short SA[128][40];    // K chunk [k][d] / Q chunk [q][d]
    __shared__ short ST[32][136];    // Vt slice [d][k] / Qt slice [d][q]
    __shared__ short P[8][32][72];   // wave-private P (row=out-idx, col=contraction)
    const int tid = threadIdx.x;
    const int w = tid >> 6, lane = tid & 63;
    const int lm = lane & 15, quad = lane >> 4;
    const float scale2 = 0.17677669529663687f * LOG2E;
    const int id = blockIdx.x;
    short (*Pw)[72] = P[w];

    if (id < 256) {
        const int b = id >> 3, h = id & 7;
        shortx8 bqf[2];
        bqf[0] = *(const shortx8*)(Qm + ((size_t)(b * 256 + w * 32 + lm)) * 256 + h * 32 + quad * 8);
        bqf[1] = *(const shortx8*)(Qm + ((size_t)(b * 256 + w * 32 + 16 + lm)) * 256 + h * 32 + quad * 8);
        floatx4 oacc[2][2] = {{{0.f,0.f,0.f,0.f},{0.f,0.f,0.f,0.f}},
                              {{0.f,0.f,0.f,0.f},{0.f,0.f,0.f,0.f}}};
        float psum[2] = {0.f, 0.f};
        const floatx4* pmp = (const floatx4*)(pad_mask + b * 512);
        for (int kc = 0; kc < 512; kc += 128) {
            if (tid < 256) {          // K chunk [128][32]
                int r = tid >> 1, dq = (tid & 1) * 16;
                const short* kp = Km + ((size_t)(b * 512 + kc + r)) * 256 + h * 32 + dq;
                *(shortx8*)&SA[r][dq] = *(const shortx8*)kp;
                *(shortx8*)&SA[r][dq + 8] = *(const shortx8*)(kp + 8);
            } else {                  // Vt slice [32][128]
                int u = tid - 256;
                int r = u >> 3, kq = (u & 7) * 16;
                const short* vp = Vt + ((size_t)(b * 256 + h * 32 + r)) * 512 + kc + kq;
                *(shortx8*)&ST[r][kq] = *(const shortx8*)vp;
                *(shortx8*)&ST[r][kq + 8] = *(const shortx8*)(vp + 8);
            }
            __syncthreads();
#pragma unroll
            for (int kh = 0; kh < 2; kh++) {
#pragma unroll
                for (int kt = 0; kt < 4; kt++) {
                    shortx8 ak = *(const shortx8*)&SA[kh * 64 + kt * 16 + lm][quad * 8];
                    floatx4 pm = pmp[kc / 4 + kh * 16 + kt * 4 + quad];
#pragma unroll
                    for (int qf = 0; qf < 2; qf++) {
                        floatx4 s = {0.f, 0.f, 0.f, 0.f};
                        s = __builtin_amdgcn_mfma_f32_16x16x32_bf16(ak, bqf[qf], s, 0, 0, 0);
                        shortx4 p4;
#pragma unroll
                        for (int r = 0; r < 4; r++) {
                            float e = __builtin_amdgcn_exp2f(
                                s[r] * scale2 + (1.0f - pm[r]) * (-10000.0f * LOG2E));
                            psum[qf] += e;
                            p4[r] = f2b(e);
                        }
                        *(long long*)&Pw[qf * 16 + lm][kt * 16 + quad * 4] = *(long long*)&p4;
                    }
                }
#pragma unroll
                for (int ks = 0; ks < 2; ks++) {
#pragma unroll
                    for (int qf = 0; qf < 2; qf++) {
                        shortx8 pb = *(const shortx8*)&Pw[qf * 16 + lm][ks * 32 + quad * 8];
#pragma unroll
                        for (int di = 0; di < 2; di++) {
                            shortx8 av = *(const shortx8*)&ST[di * 16 + lm][kh * 64 + ks * 32 + quad * 8];
                            oacc[qf][di] = __builtin_amdgcn_mfma_f32_16x16x32_bf16(av, pb, oacc[qf][di], 0, 0, 0);
                        }
                    }
                }
            }
            __syncthreads();
        }
#pragma unroll
        for (int qf = 0; qf < 2; qf++) {
            psum[qf] += __shfl_xor(psum[qf], 16, 64);
            psum[qf] += __shfl_xor(psum[qf], 32, 64);
            float inv = 1.0f / psum[qf];
            int q = w * 32 + qf * 16 + lm;
            short* op = qctx + ((size_t)(b * 256 + q)) * 256 + h * 32;
#pragma unroll
            for (int di = 0; di < 2; di++) {
                shortx4 o;
#pragma unroll
                for (int r = 0; r < 4; r++) o[r] = f2b(oacc[qf][di][r] * inv);
                *(long long*)(op + di * 16 + quad * 4) = *(long long*)&o;
            }
        }
    } else {
        const int t = id - 256;
        const int b = t >> 4, h = (t >> 1) & 7, khb = t & 1;
        shortx8 bkf[2];
        bkf[0] = *(const shortx8*)(Km + ((size_t)(b * 512 + khb * 256 + w * 32 + lm)) * 256 + h * 32 + quad * 8);
        bkf[1] = *(const shortx8*)(Km + ((size_t)(b * 512 + khb * 256 + w * 32 + 16 + lm)) * 256 + h * 32 + quad * 8);
        floatx4 oacc[2][2] = {{{0.f,0.f,0.f,0.f},{0.f,0.f,0.f,0.f}},
                              {{0.f,0.f,0.f,0.f},{0.f,0.f,0.f,0.f}}};
        float psum[2] = {0.f, 0.f};
        const floatx4* emp = (const floatx4*)(ext + b * 256);
        for (int qc = 0; qc < 256; qc += 128) {
            if (tid < 256) {          // Q chunk [128][32]
                int r = tid >> 1, dq = (tid & 1) * 16;
                const short* qp = Qm + ((size_t)(b * 256 + qc + r)) * 256 + h * 32 + dq;
                *(shortx8*)&SA[r][dq] = *(const shortx8*)qp;
                *(shortx8*)&SA[r][dq + 8] = *(const shortx8*)(qp + 8);
            } else {                  // Qt slice [32][128]
                int u = tid - 256;
                int r = u >> 3, kq = (u & 7) * 16;
                const short* tp = Qt + ((size_t)(b * 256 + h * 32 + r)) * 256 + qc + kq;
                *(shortx8*)&ST[r][kq] = *(const shortx8*)tp;
                *(shortx8*)&ST[r][kq + 8] = *(const shortx8*)(tp + 8);
            }
            __syncthreads();
#pragma unroll
            for (int qh = 0; qh < 2; qh++) {
#pragma unroll
                for (int qt = 0; qt < 4; qt++) {
                    shortx8 aq = *(const shortx8*)&SA[qh * 64 + qt * 16 + lm][quad * 8];
                    floatx4 em = emp[qc / 4 + qh * 16 + qt * 4 + quad];
#pragma unroll
                    for (int kf = 0; kf < 2; kf++) {
                        floatx4 s = {0.f, 0.f, 0.f, 0.f};
                        s = __builtin_amdgcn_mfma_f32_16x16x32_bf16(aq, bkf[kf], s, 0, 0, 0);
                        shortx4 p4;
#pragma unroll
                        for (int r = 0; r < 4; r++) {
                            float e = __builtin_amdgcn_exp2f(s[r] * scale2 + em[r] * LOG2E);
                            psum[kf] += e;
                            p4[r] = f2b(e);
                        }
                        *(long long*)&Pw[kf * 16 + lm][qt * 16 + quad * 4] = *(long long*)&p4;
                    }
                }
#pragma unroll
                for (int ks = 0; ks < 2; ks++) {
#pragma unroll
                    for (int kf = 0; kf < 2; kf++) {
                        shortx8 pb = *(const shortx8*)&Pw[kf * 16 + lm][ks * 32 + quad * 8];
#pragma unroll
                        for (int di = 0; di < 2; di++) {
                            shortx8 aT = *(const shortx8*)&ST[di * 16 + lm][qh * 64 + ks * 32 + quad * 8];
                            oacc[kf][di] = __builtin_amdgcn_mfma_f32_16x16x32_bf16(aT, pb, oacc[kf][di], 0, 0, 0);
                        }
                    }
                }
            }
            __syncthreads();
        }
#pragma unroll
        for (int kf = 0; kf < 2; kf++) {
            psum[kf] += __shfl_xor(psum[kf], 16, 64);
            psum[kf] += __shfl_xor(psum[kf], 32, 64);
            float inv = 1.0f / psum[kf];
            int k = khb * 256 + w * 32 + kf * 16 + lm;
            short* op = vctx + ((size_t)(b * 512 + k)) * 256 + h * 32;
#pragma unroll
            for (int di = 0; di < 2; di++) {
                shortx4 o;
#pragma unroll
                for (int r = 0; r < 4; r++) o[r] = f2b(oacc[kf][di][r] * inv);
                *(long long*)(op + di * 16 + quad * 4) = *(long long*)&o;
            }
        }
    }
}

// ================= PHASE 4a: tail GEMMs (64x64 tiles, f32 out) =================
__global__ __launch_bounds__(256) void phase4a_gemm(
    const short* __restrict__ qctx, const short* __restrict__ vctx,
    const short* __restrict__ val_pad, const short* __restrict__ WTo,
    const short* __restrict__ WT1, const short* __restrict__ WT2,
    float* __restrict__ obuf, float* __restrict__ tbuf) {
    __shared__ short As1[64][40];
    __shared__ short As2[64][40];
    __shared__ short Bs1[64][40];
    __shared__ short Bs2[64][40];
    const int tid = threadIdx.x;
    const int id = blockIdx.x;
    const bool is_out = id < 512;
    int t = is_out ? id : id - 512;
    const int row0 = (t >> 2) * 64, col0 = (t & 3) * 64;
    const int wv = tid >> 6, lane = tid & 63;
    const int mw = (wv & 1) * 32, nw = (wv >> 1) * 32;
    const int lm = lane & 15, quad = lane >> 4;

    floatx4 acc[2][2] = {{{0.f, 0.f, 0.f, 0.f}, {0.f, 0.f, 0.f, 0.f}},
                         {{0.f, 0.f, 0.f, 0.f}, {0.f, 0.f, 0.f, 0.f}}};

    for (int kc = 0; kc < 256; kc += 32) {
        int r = tid >> 2, kq = (tid & 3) * 8;
        if (is_out) {
            *(shortx8*)&As1[r][kq] =
                *(const shortx8*)(qctx + (size_t)(row0 + r) * 256 + kc + kq);
            *(shortx8*)&Bs1[r][kq] =
                *(const shortx8*)(WTo + (size_t)(col0 + r) * 256 + kc + kq);
        } else {
            *(shortx8*)&As1[r][kq] =
                *(const shortx8*)(vctx + (size_t)(row0 + r) * 256 + kc + kq);
            *(shortx8*)&As2[r][kq] =
                *(const shortx8*)(val_pad + (size_t)(row0 + r) * 256 + kc + kq);
            *(shortx8*)&Bs1[r][kq] =
                *(const shortx8*)(WT1 + (size_t)(col0 + r) * 256 + kc + kq);
            *(shortx8*)&Bs2[r][kq] =
                *(const shortx8*)(WT2 + (size_t)(col0 + r) * 256 + kc + kq);
        }
        __syncthreads();
        shortx8 a0 = *(const shortx8*)&As1[mw + lm][quad * 8];
        shortx8 a1 = *(const shortx8*)&As1[mw + 16 + lm][quad * 8];
        shortx8 b0 = *(const shortx8*)&Bs1[nw + lm][quad * 8];
        shortx8 b1 = *(const shortx8*)&Bs1[nw + 16 + lm][quad * 8];
        acc[0][0] = __builtin_amdgcn_mfma_f32_16x16x32_bf16(a0, b0, acc[0][0], 0, 0, 0);
        acc[0][1] = __builtin_amdgcn_mfma_f32_16x16x32_bf16(a0, b1, acc[0][1], 0, 0, 0);
        acc[1][0] = __builtin_amdgcn_mfma_f32_16x16x32_bf16(a1, b0, acc[1][0], 0, 0, 0);
        acc[1][1] = __builtin_amdgcn_mfma_f32_16x16x32_bf16(a1, b1, acc[1][1], 0, 0, 0);
        if (!is_out) {
            shortx8 c0 = *(const shortx8*)&As2[mw + lm][quad * 8];
            shortx8 c1 = *(const shortx8*)&As2[mw + 16 + lm][quad * 8];
            shortx8 d0 = *(const shortx8*)&Bs2[nw + lm][quad * 8];
            shortx8 d1 = *(const shortx8*)&Bs2[nw + 16 + lm][quad * 8];
            acc[0][0] = __builtin_amdgcn_mfma_f32_16x16x32_bf16(c0, d0, acc[0][0], 0, 0, 0);
            acc[0][1] = __builtin_amdgcn_mfma_f32_16x16x32_bf16(c0, d1, acc[0][1], 0, 0, 0);
            acc[1][0] = __builtin_amdgcn_mfma_f32_16x16x32_bf16(c1, d0, acc[1][0], 0, 0, 0);
            acc[1][1] = __builtin_amdgcn_mfma_f32_16x16x32_bf16(c1, d1, acc[1][1], 0, 0, 0);
        }
        __syncthreads();
    }
    float* C = is_out ? obuf : tbuf;
#pragma unroll
    for (int i = 0; i < 2; i++) {
#pragma unroll
        for (int j = 0; j < 2; j++) {
            int gn = col0 + nw + j * 16 + lm;
#pragma unroll
            for (int r = 0; r < 4; r++) {
                int gm = row0 + mw + i * 16 + quad * 4 + r;
                C[(size_t)gm * 256 + gn] = acc[i][j][r];
            }
        }
    }
}

// ============ PHASE 4b: LN epilogues + scatter (1 row / WAVE, no LDS) ============
__global__ __launch_bounds__(256) void phase4b_ln(
    const float* __restrict__ obuf, const float* __restrict__ bo,
    const float* __restrict__ query, const float* __restrict__ g1,
    const float* __restrict__ be1, float* __restrict__ out_q,
    const float* __restrict__ tbuf, const short* __restrict__ vctx,
    const short* __restrict__ val_pad, const float* __restrict__ b1_,
    const float* __restrict__ b2_, const float* __restrict__ g2,
    const float* __restrict__ be2, const float* __restrict__ pad_mask,
    const int* __restrict__ eb, const int* __restrict__ dst,
    float* __restrict__ sums, int* __restrict__ icnts, int E) {
    const int lane = threadIdx.x & 63, w = threadIdx.x >> 6;
    const int c0 = lane * 4;
    if (blockIdx.x < 2048) {
        int row = blockIdx.x * 4 + w;
        long long base = (long long)row * H_ + c0;
        float4 o = *(const float4*)(obuf + base);
        float4 bo4 = *(const float4*)(bo + c0);
        float4 q4 = *(const float4*)(query + base);
        float x0 = o.x + bo4.x + q4.x, x1 = o.y + bo4.y + q4.y;
        float x2 = o.z + bo4.z + q4.z, x3 = o.w + bo4.w + q4.w;
        float t = x0 + x1 + x2 + x3;
        for (int off = 32; off > 0; off >>= 1) t += __shfl_xor(t, off, 64);
        float mean = t * (1.0f / H_);
        float d0 = x0 - mean, d1 = x1 - mean, d2 = x2 - mean, d3 = x3 - mean;
        float v = d0 * d0 + d1 * d1 + d2 * d2 + d3 * d3;
        for (int off = 32; off > 0; off >>= 1) v += __shfl_xor(v, off, 64);
        float rs = rsqrtf(v * (1.0f / H_) + 1e-12f);
        float4 g = *(const float4*)(g1 + c0);
        float4 be = *(const float4*)(be1 + c0);
        float4 out;
        out.x = d0 * rs * g.x + be.x; out.y = d1 * rs * g.y + be.y;
        out.z = d2 * rs * g.z + be.z; out.w = d3 * rs * g.w + be.w;
        *(float4*)(out_q + base) = out;
    } else {
        int row = (blockIdx.x - 2048) * 4 + w;
        if (pad_mask[row] > 0.5f) {
            long long base = (long long)row * H_ + c0;
            float4 tb = *(const float4*)(tbuf + base);
            float4 b14 = *(const float4*)(b1_ + c0);
            float4 b24 = *(const float4*)(b2_ + c0);
            shortx4 vc = *(const shortx4*)(vctx + base);
            shortx4 vp = *(const shortx4*)(val_pad + base);
            float x[4];
#pragma unroll
            for (int j = 0; j < 4; j++) {
                float tv = (j == 0) ? tb.x : (j == 1) ? tb.y : (j == 2) ? tb.z : tb.w;
                float bb1 = (j == 0) ? b14.x : (j == 1) ? b14.y : (j == 2) ? b14.z : b14.w;
                float bb2 = (j == 0) ? b24.x : (j == 1) ? b24.y : (j == 2) ? b24.z : b24.w;
                float th = 1.0f / (1.0f + __expf(-(tv + bb1 + bb2)));
                x[j] = th * b2f(vc[j]) + (1.0f - th) * b2f(vp[j]);
            }
            float t = x[0] + x[1] + x[2] + x[3];
            for (int off = 32; off > 0; off >>= 1) t += __shfl_xor(t, off, 64);
            float mean = t * (1.0f / H_);
            float d0 = x[0] - mean, d1 = x[1] - mean, d2 = x[2] - mean, d3 = x[3] - mean;
            float v = d0 * d0 + d1 * d1 + d2 * d2 + d3 * d3;
            for (int off = 32; off > 0; off >>= 1) v += __shfl_xor(v, off, 64);
            float rs = rsqrtf(v * (1.0f / H_) + 1e-12f);
            float4 g = *(const float4*)(g2 + c0);
            float4 be = *(const float4*)(be2 + c0);
            float y0 = d0 * rs * g.x + be.x, y1 = d1 * rs * g.y + be.y;
            float y2 = d2 * rs * g.z + be.z, y3 = d3 * rs * g.w + be.w;
            int b = row >> 9;
            int lo = 0, hi = E;
            while (lo < hi) { int mid = (lo + hi) >> 1; if (eb[mid] < b) lo = mid + 1; else hi = mid; }
            int d = dst[lo + (row & 511)];
            float* sp = sums + (size_t)d * 256 + c0;
            atomicAdd(sp + 0, y0);
            atomicAdd(sp + 1, y1);
            atomicAdd(sp + 2, y2);
            atomicAdd(sp + 3, y3);
            if (lane == 0) atomicAdd(&icnts[d], 1);
        }
    }
}

// ================= PHASE 5: finalize =================
__global__ __launch_bounds__(256) void finalize_graph(
    const float* __restrict__ sums, const int* __restrict__ icnts,
    const float* __restrict__ graph, float* __restrict__ out_g) {
    int n = blockIdx.x, c = threadIdx.x;
    long long idx = (long long)n * H_ + c;
    int cnt = icnts[n];
    out_g[idx] = (cnt > 0) ? sums[idx] / (float)cnt : graph[idx];
}

extern "C" void kernel_launch(void* const* d_in, const int* in_sizes, int n_in,
                              void* d_out, int out_size, void* d_ws, size_t ws_size,
                              hipStream_t stream) {
    const float* ext_mask = (const float*)d_in[0];
    const float* query    = (const float*)d_in[1];
    const float* rel      = (const float*)d_in[2];
    const float* graph    = (const float*)d_in[3];
    const int*  src      = (const int*)d_in[4];
    const int*  dst      = (const int*)d_in[5];
    const int*  eb       = (const int*)d_in[6];
    const int*  ep       = (const int*)d_in[7];
    const float* pad_mask = (const float*)d_in[8];
    const float* Wq = (const float*)d_in[9];  const float* bq = (const float*)d_in[10];
    const float* Wk = (const float*)d_in[11]; const float* bk = (const float*)d_in[12];
    const float* Wv = (const float*)d_in[13]; const float* bv = (const float*)d_in[14];
    const float* Wo = (const float*)d_in[15]; const float* bo = (const float*)d_in[16];
    const float* g1 = (const float*)d_in[17]; const float* be1 = (const float*)d_in[18];
    const float* W1 = (const float*)d_in[19]; const float* b1 = (const float*)d_in[20];
    const float* W2 = (const float*)d_in[21]; const float* b2 = (const float*)d_in[22];
    const float* g2 = (const float*)d_in[23]; const float* be2 = (const float*)d_in[24];
    const int E = in_sizes[2] / H_;
    (void)ep;

    float* out_g = (float*)d_out;
    float* out_q = (float*)d_out + (size_t)N_ * H_;

    short* sp = (short*)d_ws;
    short* key_pad = sp; sp += (size_t)B_ * LK_ * 2 * H_;
    short* val_pad = sp; sp += (size_t)B_ * LK_ * H_;
    short* Qb      = sp; sp += (size_t)B_ * LQ_ * H_;
    short* Kb      = sp; sp += (size_t)B_ * LK_ * H_;
    short* Vt      = sp; sp += (size_t)B_ * H_ * LK_;   // [b][c][k]
    short* Qt      = sp; sp += (size_t)B_ * H_ * LQ_;   // [b][c][q]
    short* qctx    = sp; sp += (size_t)B_ * LQ_ * H_;
    short* vctx    = sp; sp += (size_t)B_ * LK_ * H_;
    short* WT      = sp; sp += 458752;
    short* WTo = WT + 262144;
    short* WT1 = WT + 327680;
    short* WT2 = WT + 393216;
    float* fp = (float*)(((size_t)sp + 15) & ~(size_t)15);
    float* sums = fp; fp += (size_t)N_ * H_;
    int*   icnts = (int*)fp; fp += N_;
    float* obuf = fp; fp += (size_t)B_ * LQ_ * H_;   // f32 [8192,256]
    float* tbuf = fp; fp += (size_t)B_ * LK_ * H_;   // f32 [16384,256]

    phase1<<<10496, 256, 0, stream>>>(graph, rel, src, dst, eb, pad_mask,
                                      Wq, Wk, Wv, Wo, W1, W2,
                                      WT, key_pad, val_pad, sums, E);
    phase2_gemm<<<3072, 256, 0, stream>>>(query, key_pad, val_pad, WT,
                                          bq, bk, bv, Qb, Kb, Vt, Qt);
    phase3_attn<<<768, 512, 0, stream>>>(Qb, Kb, Vt, Qt, pad_mask, ext_mask,
                                         qctx, vctx);
    phase4a_gemm<<<1536, 256, 0, stream>>>(qctx, vctx, val_pad, WTo, WT1, WT2,
                                           obuf, tbuf);
    phase4b_ln<<<6144, 256, 0, stream>>>(obuf, bo, query, g1, be1, out_q,
                                         tbuf, vctx, val_pad, b1, b2, g2, be2,
                                         pad_mask, eb, dst, sums, icnts, E);
    finalize_graph<<<N_, 256, 0, stream>>>(sums, icnts, graph, out_g);
}

// Round 3
// 245.131 us; speedup vs baseline: 1.1906x; 1.1533x over previous
//
#include <hip/hip_runtime.h>
#include <hip/hip_bf16.h>
#include <string.h>

#define B_ 32
#define LQ_ 256
#define H_ 256
#define NH_ 8
#define LK_ 512
#define N_ 8192
#define DH_ 32

typedef float floatx4 __attribute__((ext_vector_type(4)));
typedef short shortx8 __attribute__((ext_vector_type(8)));
typedef short shortx4 __attribute__((ext_vector_type(4)));

__device__ __forceinline__ short f2b(float f) {
    __hip_bfloat16 h = __float2bfloat16(f);
    short s;
    __builtin_memcpy(&s, &h, 2);
    return s;
}
__device__ __forceinline__ float b2f(short s) {
    unsigned u = ((unsigned)(unsigned short)s) << 16;
    float f;
    __builtin_memcpy(&f, &u, 4);
    return f;
}

#define LOG2E 1.44269504088896f

// ================= PHASE 1: head/-row2e init ∥ prep_w ∥ gather =================
__global__ __launch_bounds__(256) void phase1(
    const float* __restrict__ graph, const float* __restrict__ rel,
    const int* __restrict__ src, const int* __restrict__ dst,
    const int* __restrict__ eb, const int* __restrict__ ep,
    const float* __restrict__ pad_mask,
    const float* __restrict__ Wq, const float* __restrict__ Wk,
    const float* __restrict__ Wv, const float* __restrict__ Wo,
    const float* __restrict__ W1, const float* __restrict__ W2,
    short* __restrict__ WT, short* __restrict__ key_pad,
    short* __restrict__ val_pad, int* __restrict__ head,
    int* __restrict__ row2e, int E) {
    const int bid = blockIdx.x, tid = threadIdx.x;
    if (bid < 8192) {
        int row = bid * 2 + (tid >> 7);
        int t = tid & 127;
        int b = row >> 9, p = row & 511;
        bool valid = pad_mask[row] > 0.5f;
        size_t krow = (size_t)row * 512;
        size_t vrow = (size_t)row * 256;
        int kc = t * 4, vc = t * 2;
        if (valid) {
            int lo = 0, hi = E;
            while (lo < hi) { int mid = (lo + hi) >> 1; if (eb[mid] < b) lo = mid + 1; else hi = mid; }
            int e = lo + p;
            int s = src[e], d = dst[e];
            const float* sp = (kc < 256) ? (graph + (size_t)s * 256 + kc)
                                         : (rel + (size_t)e * 256 + (kc - 256));
            float4 k4 = *(const float4*)sp;
            key_pad[krow + kc + 0] = f2b(k4.x);
            key_pad[krow + kc + 1] = f2b(k4.y);
            key_pad[krow + kc + 2] = f2b(k4.z);
            key_pad[krow + kc + 3] = f2b(k4.w);
            float2 v2 = *(const float2*)(graph + (size_t)d * 256 + vc);
            val_pad[vrow + vc + 0] = f2b(v2.x);
            val_pad[vrow + vc + 1] = f2b(v2.y);
        } else {
            *(long long*)&key_pad[krow + kc] = 0;
            *(int*)&val_pad[vrow + vc] = 0;
        }
    } else if (bid < 9984) {
        int i = (bid - 8192) * 256 + tid;
        const float* s;
        int K, loc;
        if (i < 65536) { s = Wq; K = 256; loc = i; }
        else if (i < 196608) { s = Wk; K = 512; loc = i - 65536; }
        else {
            int m = (i - 196608) >> 16;
            loc = (i - 196608) & 65535;
            K = 256;
            s = (m == 0) ? Wv : (m == 1) ? Wo : (m == 2) ? W1 : W2;
        }
        int n = loc / K, k = loc - n * K;
        WT[i] = f2b(s[(size_t)k * 256 + n]);
    } else {
        int i = (bid - 9984) * 256 + tid;   // 32 blocks -> 8192 threads
        if (i < 8192) head[i] = -1;
        for (int j = i; j < E; j += 8192)
            row2e[eb[j] * 512 + ep[j]] = j;
    }
}

// ================= PHASE 2: QKV GEMMs (+ transposed Vt, Qt) =================
__global__ __launch_bounds__(256) void phase2_gemm(
    const float* __restrict__ query, const short* __restrict__ key_pad,
    const short* __restrict__ val_pad, const short* __restrict__ WT,
    const float* __restrict__ bq, const float* __restrict__ bk,
    const float* __restrict__ bv,
    short* __restrict__ Qb, short* __restrict__ Kb,
    short* __restrict__ Vt, short* __restrict__ Qt) {
    __shared__ short As[64][40];
    __shared__ short Bs[64][40];
    const int tid = threadIdx.x;
    const int id = blockIdx.x;
    const float* Af = nullptr; const short* Ab = nullptr;
    const float* Bf = nullptr; const short* Bb = nullptr;
    const float* bias; short* C;
    size_t cbase; int cstride, K; bool biasM;
    if (id < 512) {
        int rb = id >> 2, cb = id & 3;
        Af = query + (size_t)(rb * 64) * 256; K = 256;
        Bb = WT + (size_t)(cb * 64) * 256;
        bias = bq + cb * 64; biasM = false;
        C = Qb; cbase = (size_t)(rb * 64) * 256 + cb * 64; cstride = 256;
    } else if (id < 1536) {
        int t = id - 512; int rb = t >> 2, cb = t & 3;
        Ab = key_pad + (size_t)(rb * 64) * 512; K = 512;
        Bb = WT + 65536 + (size_t)(cb * 64) * 512;
        bias = bk + cb * 64; biasM = false;
        C = Kb; cbase = (size_t)(rb * 64) * 256 + cb * 64; cstride = 256;
    } else if (id < 2560) {
        int t = id - 1536; int b = t >> 5, ct = (t >> 3) & 3, kt = t & 7;
        Ab = WT + 196608 + (size_t)(ct * 64) * 256; K = 256;
        Bb = val_pad + ((size_t)(b * 512 + kt * 64)) * 256;
        bias = bv + ct * 64; biasM = true;
        C = Vt; cbase = ((size_t)(b * 256 + ct * 64)) * 512 + kt * 64; cstride = 512;
    } else {
        int t = id - 2560; int b = t >> 4, ct = (t >> 2) & 3, qt = t & 3;
        Ab = WT + (size_t)(ct * 64) * 256; K = 256;
        Bf = query + ((size_t)(b * 256 + qt * 64)) * 256;
        bias = bq + ct * 64; biasM = true;
        C = Qt; cbase = ((size_t)(b * 256 + ct * 64)) * 256 + qt * 64; cstride = 256;
    }
    const int wv = tid >> 6, lane = tid & 63;
    const int mw = (wv & 1) * 32, nw = (wv >> 1) * 32;
    const int lm = lane & 15, quad = lane >> 4;

    floatx4 acc[2][2] = {{{0.f, 0.f, 0.f, 0.f}, {0.f, 0.f, 0.f, 0.f}},
                         {{0.f, 0.f, 0.f, 0.f}, {0.f, 0.f, 0.f, 0.f}}};

    for (int kc = 0; kc < K; kc += 32) {
        int r = tid >> 2, kq = (tid & 3) * 8;
        if (Af) {
            const float* ap = Af + (size_t)r * K + kc + kq;
            float4 a1 = *(const float4*)ap, a2 = *(const float4*)(ap + 4);
            As[r][kq + 0] = f2b(a1.x); As[r][kq + 1] = f2b(a1.y);
            As[r][kq + 2] = f2b(a1.z); As[r][kq + 3] = f2b(a1.w);
            As[r][kq + 4] = f2b(a2.x); As[r][kq + 5] = f2b(a2.y);
            As[r][kq + 6] = f2b(a2.z); As[r][kq + 7] = f2b(a2.w);
        } else {
            *(shortx8*)&As[r][kq] = *(const shortx8*)(Ab + (size_t)r * K + kc + kq);
        }
        if (Bf) {
            const float* bp = Bf + (size_t)r * K + kc + kq;
            float4 b1 = *(const float4*)bp, b2 = *(const float4*)(bp + 4);
            Bs[r][kq + 0] = f2b(b1.x); Bs[r][kq + 1] = f2b(b1.y);
            Bs[r][kq + 2] = f2b(b1.z); Bs[r][kq + 3] = f2b(b1.w);
            Bs[r][kq + 4] = f2b(b2.x); Bs[r][kq + 5] = f2b(b2.y);
            Bs[r][kq + 6] = f2b(b2.z); Bs[r][kq + 7] = f2b(b2.w);
        } else {
            *(shortx8*)&Bs[r][kq] = *(const shortx8*)(Bb + (size_t)r * K + kc + kq);
        }
        __syncthreads();
        shortx8 a0 = *(const shortx8*)&As[mw + lm][quad * 8];
        shortx8 a1 = *(const shortx8*)&As[mw + 16 + lm][quad * 8];
        shortx8 b0 = *(const shortx8*)&Bs[nw + lm][quad * 8];
        shortx8 b1 = *(const shortx8*)&Bs[nw + 16 + lm][quad * 8];
        acc[0][0] = __builtin_amdgcn_mfma_f32_16x16x32_bf16(a0, b0, acc[0][0], 0, 0, 0);
        acc[0][1] = __builtin_amdgcn_mfma_f32_16x16x32_bf16(a0, b1, acc[0][1], 0, 0, 0);
        acc[1][0] = __builtin_amdgcn_mfma_f32_16x16x32_bf16(a1, b0, acc[1][0], 0, 0, 0);
        acc[1][1] = __builtin_amdgcn_mfma_f32_16x16x32_bf16(a1, b1, acc[1][1], 0, 0, 0);
        __syncthreads();
    }
#pragma unroll
    for (int i = 0; i < 2; i++) {
#pragma unroll
        for (int j = 0; j < 2; j++) {
            int gn = nw + j * 16 + lm;
#pragma unroll
            for (int r = 0; r < 4; r++) {
                int gm = mw + i * 16 + quad * 4 + r;
                float bvv = biasM ? bias[gm] : bias[gn];
                C[cbase + (size_t)gm * cstride + gn] = f2b(acc[i][j][r] + bvv);
            }
        }
    }
}

// ================= PHASE 3: attention, (b,h)-blocked for exact reuse =========
__global__ __launch_bounds__(512, 4) void phase3_attn(
    const short* __restrict__ Qm, const short* __restrict__ Km,
    const short* __restrict__ Vt, const short* __restrict__ Qt,
    const float* __restrict__ pad_mask, const float* __restrict__ ext,
    short* __restrict__ qctx, short* __restrict__ vctx) {
    __shared__ short SA[128][40];    // K chunk [k][d] / Q chunk [q][d]
    __shared__ short ST[32][136];    // Vt slice [d][k] / Qt slice [d][q]
    __shared__ short P[8][32][72];   // wave-private P (row=out-idx, col=contraction)
    const int tid = threadIdx.x;
    const int w = tid >> 6, lane = tid & 63;
    const int lm = lane & 15, quad = lane >> 4;
    const float scale2 = 0.17677669529663687f * LOG2E;
    const int id = blockIdx.x;
    short (*Pw)[72] = P[w];

    if (id < 256) {
        const int b = id >> 3, h = id & 7;
        shortx8 bqf[2];
        bqf[0] = *(const shortx8*)(Qm + ((size_t)(b * 256 + w * 32 + lm)) * 256 + h * 32 + quad * 8);
        bqf[1] = *(const shortx8*)(Qm + ((size_t)(b * 256 + w * 32 + 16 + lm)) * 256 + h * 32 + quad * 8);
        floatx4 oacc[2][2] = {{{0.f,0.f,0.f,0.f},{0.f,0.f,0.f,0.f}},
                              {{0.f,0.f,0.f,0.f},{0.f,0.f,0.f,0.f}}};
        float psum[2] = {0.f, 0.f};
        const floatx4* pmp = (const floatx4*)(pad_mask + b * 512);
        for (int kc = 0; kc < 512; kc += 128) {
            if (tid < 256) {          // K chunk [128][32]
                int r = tid >> 1, dq = (tid & 1) * 16;
                const short* kp = Km + ((size_t)(b * 512 + kc + r)) * 256 + h * 32 + dq;
                *(shortx8*)&SA[r][dq] = *(const shortx8*)kp;
                *(shortx8*)&SA[r][dq + 8] = *(const shortx8*)(kp + 8);
            } else {                  // Vt slice [32][128]
                int u = tid - 256;
                int r = u >> 3, kq = (u & 7) * 16;
                const short* vp = Vt + ((size_t)(b * 256 + h * 32 + r)) * 512 + kc + kq;
                *(shortx8*)&ST[r][kq] = *(const shortx8*)vp;
                *(shortx8*)&ST[r][kq + 8] = *(const shortx8*)(vp + 8);
            }
            __syncthreads();
#pragma unroll
            for (int kh = 0; kh < 2; kh++) {
#pragma unroll
                for (int kt = 0; kt < 4; kt++) {
                    shortx8 ak = *(const shortx8*)&SA[kh * 64 + kt * 16 + lm][quad * 8];
                    floatx4 pm = pmp[kc / 4 + kh * 16 + kt * 4 + quad];
#pragma unroll
                    for (int qf = 0; qf < 2; qf++) {
                        floatx4 s = {0.f, 0.f, 0.f, 0.f};
                        s = __builtin_amdgcn_mfma_f32_16x16x32_bf16(ak, bqf[qf], s, 0, 0, 0);
                        shortx4 p4;
#pragma unroll
                        for (int r = 0; r < 4; r++) {
                            float e = __builtin_amdgcn_exp2f(
                                s[r] * scale2 + (1.0f - pm[r]) * (-10000.0f * LOG2E));
                            psum[qf] += e;
                            p4[r] = f2b(e);
                        }
                        *(long long*)&Pw[qf * 16 + lm][kt * 16 + quad * 4] = *(long long*)&p4;
                    }
                }
#pragma unroll
                for (int ks = 0; ks < 2; ks++) {
#pragma unroll
                    for (int qf = 0; qf < 2; qf++) {
                        shortx8 pb = *(const shortx8*)&Pw[qf * 16 + lm][ks * 32 + quad * 8];
#pragma unroll
                        for (int di = 0; di < 2; di++) {
                            shortx8 av = *(const shortx8*)&ST[di * 16 + lm][kh * 64 + ks * 32 + quad * 8];
                            oacc[qf][di] = __builtin_amdgcn_mfma_f32_16x16x32_bf16(av, pb, oacc[qf][di], 0, 0, 0);
                        }
                    }
                }
            }
            __syncthreads();
        }
#pragma unroll
        for (int qf = 0; qf < 2; qf++) {
            psum[qf] += __shfl_xor(psum[qf], 16, 64);
            psum[qf] += __shfl_xor(psum[qf], 32, 64);
            float inv = 1.0f / psum[qf];
            int q = w * 32 + qf * 16 + lm;
            short* op = qctx + ((size_t)(b * 256 + q)) * 256 + h * 32;
#pragma unroll
            for (int di = 0; di < 2; di++) {
                shortx4 o;
#pragma unroll
                for (int r = 0; r < 4; r++) o[r] = f2b(oacc[qf][di][r] * inv);
                *(long long*)(op + di * 16 + quad * 4) = *(long long*)&o;
            }
        }
    } else {
        const int t = id - 256;
        const int b = t >> 4, h = (t >> 1) & 7, khb = t & 1;
        shortx8 bkf[2];
        bkf[0] = *(const shortx8*)(Km + ((size_t)(b * 512 + khb * 256 + w * 32 + lm)) * 256 + h * 32 + quad * 8);
        bkf[1] = *(const shortx8*)(Km + ((size_t)(b * 512 + khb * 256 + w * 32 + 16 + lm)) * 256 + h * 32 + quad * 8);
        floatx4 oacc[2][2] = {{{0.f,0.f,0.f,0.f},{0.f,0.f,0.f,0.f}},
                              {{0.f,0.f,0.f,0.f},{0.f,0.f,0.f,0.f}}};
        float psum[2] = {0.f, 0.f};
        const floatx4* emp = (const floatx4*)(ext + b * 256);
        for (int qc = 0; qc < 256; qc += 128) {
            if (tid < 256) {          // Q chunk [128][32]
                int r = tid >> 1, dq = (tid & 1) * 16;
                const short* qp = Qm + ((size_t)(b * 256 + qc + r)) * 256 + h * 32 + dq;
                *(shortx8*)&SA[r][dq] = *(const shortx8*)qp;
                *(shortx8*)&SA[r][dq + 8] = *(const shortx8*)(qp + 8);
            } else {                  // Qt slice [32][128]
                int u = tid - 256;
                int r = u >> 3, kq = (u & 7) * 16;
                const short* tp = Qt + ((size_t)(b * 256 + h * 32 + r)) * 256 + qc + kq;
                *(shortx8*)&ST[r][kq] = *(const shortx8*)tp;
                *(shortx8*)&ST[r][kq + 8] = *(const shortx8*)(tp + 8);
            }
            __syncthreads();
#pragma unroll
            for (int qh = 0; qh < 2; qh++) {
#pragma unroll
                for (int qt = 0; qt < 4; qt++) {
                    shortx8 aq = *(const shortx8*)&SA[qh * 64 + qt * 16 + lm][quad * 8];
                    floatx4 em = emp[qc / 4 + qh * 16 + qt * 4 + quad];
#pragma unroll
                    for (int kf = 0; kf < 2; kf++) {
                        floatx4 s = {0.f, 0.f, 0.f, 0.f};
                        s = __builtin_amdgcn_mfma_f32_16x16x32_bf16(aq, bkf[kf], s, 0, 0, 0);
                        shortx4 p4;
#pragma unroll
                        for (int r = 0; r < 4; r++) {
                            float e = __builtin_amdgcn_exp2f(s[r] * scale2 + em[r] * LOG2E);
                            psum[kf] += e;
                            p4[r] = f2b(e);
                        }
                        *(long long*)&Pw[kf * 16 + lm][qt * 16 + quad * 4] = *(long long*)&p4;
                    }
                }
#pragma unroll
                for (int ks = 0; ks < 2; ks++) {
#pragma unroll
                    for (int kf = 0; kf < 2; kf++) {
                        shortx8 pb = *(const shortx8*)&Pw[kf * 16 + lm][ks * 32 + quad * 8];
#pragma unroll
                        for (int di = 0; di < 2; di++) {
                            shortx8 aT = *(const shortx8*)&ST[di * 16 + lm][qh * 64 + ks * 32 + quad * 8];
                            oacc[kf][di] = __builtin_amdgcn_mfma_f32_16x16x32_bf16(aT, pb, oacc[kf][di], 0, 0, 0);
                        }
                    }
                }
            }
            __syncthreads();
        }
#pragma unroll
        for (int kf = 0; kf < 2; kf++) {
            psum[kf] += __shfl_xor(psum[kf], 16, 64);
            psum[kf] += __shfl_xor(psum[kf], 32, 64);
            float inv = 1.0f / psum[kf];
            int k = khb * 256 + w * 32 + kf * 16 + lm;
            short* op = vctx + ((size_t)(b * 512 + k)) * 256 + h * 32;
#pragma unroll
            for (int di = 0; di < 2; di++) {
                shortx4 o;
#pragma unroll
                for (int r = 0; r < 4; r++) o[r] = f2b(oacc[kf][di][r] * inv);
                *(long long*)(op + di * 16 + quad * 4) = *(long long*)&o;
            }
        }
    }
}

// ================= PHASE 4a: tail GEMMs (64x64 tiles, f32 out) =================
__global__ __launch_bounds__(256) void phase4a_gemm(
    const short* __restrict__ qctx, const short* __restrict__ vctx,
    const short* __restrict__ val_pad, const short* __restrict__ WTo,
    const short* __restrict__ WT1, const short* __restrict__ WT2,
    float* __restrict__ obuf, float* __restrict__ tbuf) {
    __shared__ short As1[64][40];
    __shared__ short As2[64][40];
    __shared__ short Bs1[64][40];
    __shared__ short Bs2[64][40];
    const int tid = threadIdx.x;
    const int id = blockIdx.x;
    const bool is_out = id < 512;
    int t = is_out ? id : id - 512;
    const int row0 = (t >> 2) * 64, col0 = (t & 3) * 64;
    const int wv = tid >> 6, lane = tid & 63;
    const int mw = (wv & 1) * 32, nw = (wv >> 1) * 32;
    const int lm = lane & 15, quad = lane >> 4;

    floatx4 acc[2][2] = {{{0.f, 0.f, 0.f, 0.f}, {0.f, 0.f, 0.f, 0.f}},
                         {{0.f, 0.f, 0.f, 0.f}, {0.f, 0.f, 0.f, 0.f}}};

    for (int kc = 0; kc < 256; kc += 32) {
        int r = tid >> 2, kq = (tid & 3) * 8;
        if (is_out) {
            *(shortx8*)&As1[r][kq] =
                *(const shortx8*)(qctx + (size_t)(row0 + r) * 256 + kc + kq);
            *(shortx8*)&Bs1[r][kq] =
                *(const shortx8*)(WTo + (size_t)(col0 + r) * 256 + kc + kq);
        } else {
            *(shortx8*)&As1[r][kq] =
                *(const shortx8*)(vctx + (size_t)(row0 + r) * 256 + kc + kq);
            *(shortx8*)&As2[r][kq] =
                *(const shortx8*)(val_pad + (size_t)(row0 + r) * 256 + kc + kq);
            *(shortx8*)&Bs1[r][kq] =
                *(const shortx8*)(WT1 + (size_t)(col0 + r) * 256 + kc + kq);
            *(shortx8*)&Bs2[r][kq] =
                *(const shortx8*)(WT2 + (size_t)(col0 + r) * 256 + kc + kq);
        }
        __syncthreads();
        shortx8 a0 = *(const shortx8*)&As1[mw + lm][quad * 8];
        shortx8 a1 = *(const shortx8*)&As1[mw + 16 + lm][quad * 8];
        shortx8 b0 = *(const shortx8*)&Bs1[nw + lm][quad * 8];
        shortx8 b1 = *(const shortx8*)&Bs1[nw + 16 + lm][quad * 8];
        acc[0][0] = __builtin_amdgcn_mfma_f32_16x16x32_bf16(a0, b0, acc[0][0], 0, 0, 0);
        acc[0][1] = __builtin_amdgcn_mfma_f32_16x16x32_bf16(a0, b1, acc[0][1], 0, 0, 0);
        acc[1][0] = __builtin_amdgcn_mfma_f32_16x16x32_bf16(a1, b0, acc[1][0], 0, 0, 0);
        acc[1][1] = __builtin_amdgcn_mfma_f32_16x16x32_bf16(a1, b1, acc[1][1], 0, 0, 0);
        if (!is_out) {
            shortx8 c0 = *(const shortx8*)&As2[mw + lm][quad * 8];
            shortx8 c1 = *(const shortx8*)&As2[mw + 16 + lm][quad * 8];
            shortx8 d0 = *(const shortx8*)&Bs2[nw + lm][quad * 8];
            shortx8 d1 = *(const shortx8*)&Bs2[nw + 16 + lm][quad * 8];
            acc[0][0] = __builtin_amdgcn_mfma_f32_16x16x32_bf16(c0, d0, acc[0][0], 0, 0, 0);
            acc[0][1] = __builtin_amdgcn_mfma_f32_16x16x32_bf16(c0, d1, acc[0][1], 0, 0, 0);
            acc[1][0] = __builtin_amdgcn_mfma_f32_16x16x32_bf16(c1, d0, acc[1][0], 0, 0, 0);
            acc[1][1] = __builtin_amdgcn_mfma_f32_16x16x32_bf16(c1, d1, acc[1][1], 0, 0, 0);
        }
        __syncthreads();
    }
    float* C = is_out ? obuf : tbuf;
#pragma unroll
    for (int i = 0; i < 2; i++) {
#pragma unroll
        for (int j = 0; j < 2; j++) {
            int gn = col0 + nw + j * 16 + lm;
#pragma unroll
            for (int r = 0; r < 4; r++) {
                int gm = row0 + mw + i * 16 + quad * 4 + r;
                C[(size_t)gm * 256 + gn] = acc[i][j][r];
            }
        }
    }
}

// ===== PHASE 4b: LN epilogues (1 row / wave); gate writes y in-place into tbuf
//       and pushes its row onto a per-dst lock-free list (1 atomicExch / row) ====
__global__ __launch_bounds__(256) void phase4b_ln(
    const float* __restrict__ obuf, const float* __restrict__ bo,
    const float* __restrict__ query, const float* __restrict__ g1,
    const float* __restrict__ be1, float* __restrict__ out_q,
    float* __restrict__ tbuf, const short* __restrict__ vctx,
    const short* __restrict__ val_pad, const float* __restrict__ b1_,
    const float* __restrict__ b2_, const float* __restrict__ g2,
    const float* __restrict__ be2, const float* __restrict__ pad_mask,
    const int* __restrict__ row2e, const int* __restrict__ dst,
    int* __restrict__ head, int* __restrict__ nxt) {
    const int lane = threadIdx.x & 63, w = threadIdx.x >> 6;
    const int c0 = lane * 4;
    if (blockIdx.x < 2048) {
        int row = blockIdx.x * 4 + w;
        long long base = (long long)row * H_ + c0;
        float4 o = *(const float4*)(obuf + base);
        float4 bo4 = *(const float4*)(bo + c0);
        float4 q4 = *(const float4*)(query + base);
        float x0 = o.x + bo4.x + q4.x, x1 = o.y + bo4.y + q4.y;
        float x2 = o.z + bo4.z + q4.z, x3 = o.w + bo4.w + q4.w;
        float t = x0 + x1 + x2 + x3;
        for (int off = 32; off > 0; off >>= 1) t += __shfl_xor(t, off, 64);
        float mean = t * (1.0f / H_);
        float d0 = x0 - mean, d1 = x1 - mean, d2 = x2 - mean, d3 = x3 - mean;
        float v = d0 * d0 + d1 * d1 + d2 * d2 + d3 * d3;
        for (int off = 32; off > 0; off >>= 1) v += __shfl_xor(v, off, 64);
        float rs = rsqrtf(v * (1.0f / H_) + 1e-12f);
        float4 g = *(const float4*)(g1 + c0);
        float4 be = *(const float4*)(be1 + c0);
        float4 out;
        out.x = d0 * rs * g.x + be.x; out.y = d1 * rs * g.y + be.y;
        out.z = d2 * rs * g.z + be.z; out.w = d3 * rs * g.w + be.w;
        *(float4*)(out_q + base) = out;
    } else {
        int row = (blockIdx.x - 2048) * 4 + w;
        if (pad_mask[row] > 0.5f) {
            long long base = (long long)row * H_ + c0;
            float4 tb = *(const float4*)(tbuf + base);
            float4 b14 = *(const float4*)(b1_ + c0);
            float4 b24 = *(const float4*)(b2_ + c0);
            shortx4 vc = *(const shortx4*)(vctx + base);
            shortx4 vp = *(const shortx4*)(val_pad + base);
            float x[4];
#pragma unroll
            for (int j = 0; j < 4; j++) {
                float tv = (j == 0) ? tb.x : (j == 1) ? tb.y : (j == 2) ? tb.z : tb.w;
                float bb1 = (j == 0) ? b14.x : (j == 1) ? b14.y : (j == 2) ? b14.z : b14.w;
                float bb2 = (j == 0) ? b24.x : (j == 1) ? b24.y : (j == 2) ? b24.z : b24.w;
                float th = 1.0f / (1.0f + __expf(-(tv + bb1 + bb2)));
                x[j] = th * b2f(vc[j]) + (1.0f - th) * b2f(vp[j]);
            }
            float t = x[0] + x[1] + x[2] + x[3];
            for (int off = 32; off > 0; off >>= 1) t += __shfl_xor(t, off, 64);
            float mean = t * (1.0f / H_);
            float d0 = x[0] - mean, d1 = x[1] - mean, d2 = x[2] - mean, d3 = x[3] - mean;
            float v = d0 * d0 + d1 * d1 + d2 * d2 + d3 * d3;
            for (int off = 32; off > 0; off >>= 1) v += __shfl_xor(v, off, 64);
            float rs = rsqrtf(v * (1.0f / H_) + 1e-12f);
            float4 g = *(const float4*)(g2 + c0);
            float4 be = *(const float4*)(be2 + c0);
            float4 y4;
            y4.x = d0 * rs * g.x + be.x; y4.y = d1 * rs * g.y + be.y;
            y4.z = d2 * rs * g.z + be.z; y4.w = d3 * rs * g.w + be.w;
            *(float4*)(tbuf + base) = y4;   // in-place: same addresses just read
            if (lane == 0) {
                int d = dst[row2e[row]];
                int prev = atomicExch(&head[d], row);
                nxt[row] = prev;
            }
        }
    }
}

// ================= PHASE 5: finalize (walk per-node edge list) =================
__global__ __launch_bounds__(256) void finalize_graph(
    const int* __restrict__ head, const int* __restrict__ nxt,
    const float* __restrict__ yrows, const float* __restrict__ graph,
    float* __restrict__ out_g) {
    int n = blockIdx.x, c = threadIdx.x;
    long long idx = (long long)n * H_ + c;
    int e = head[n];
    if (e < 0) { out_g[idx] = graph[idx]; return; }
    float acc = 0.f;
    int cnt = 0;
    while (e >= 0) {
        acc += yrows[(size_t)e * H_ + c];
        cnt++;
        e = nxt[e];
    }
    out_g[idx] = acc / (float)cnt;
}

extern "C" void kernel_launch(void* const* d_in, const int* in_sizes, int n_in,
                              void* d_out, int out_size, void* d_ws, size_t ws_size,
                              hipStream_t stream) {
    const float* ext_mask = (const float*)d_in[0];
    const float* query    = (const float*)d_in[1];
    const float* rel      = (const float*)d_in[2];
    const float* graph    = (const float*)d_in[3];
    const int*  src      = (const int*)d_in[4];
    const int*  dst      = (const int*)d_in[5];
    const int*  eb       = (const int*)d_in[6];
    const int*  ep       = (const int*)d_in[7];
    const float* pad_mask = (const float*)d_in[8];
    const float* Wq = (const float*)d_in[9];  const float* bq = (const float*)d_in[10];
    const float* Wk = (const float*)d_in[11]; const float* bk = (const float*)d_in[12];
    const float* Wv = (const float*)d_in[13]; const float* bv = (const float*)d_in[14];
    const float* Wo = (const float*)d_in[15]; const float* bo = (const float*)d_in[16];
    const float* g1 = (const float*)d_in[17]; const float* be1 = (const float*)d_in[18];
    const float* W1 = (const float*)d_in[19]; const float* b1 = (const float*)d_in[20];
    const float* W2 = (const float*)d_in[21]; const float* b2 = (const float*)d_in[22];
    const float* g2 = (const float*)d_in[23]; const float* be2 = (const float*)d_in[24];
    const int E = in_sizes[2] / H_;

    float* out_g = (float*)d_out;
    float* out_q = (float*)d_out + (size_t)N_ * H_;

    short* sp = (short*)d_ws;
    short* key_pad = sp; sp += (size_t)B_ * LK_ * 2 * H_;
    short* val_pad = sp; sp += (size_t)B_ * LK_ * H_;
    short* Qb      = sp; sp += (size_t)B_ * LQ_ * H_;
    short* Kb      = sp; sp += (size_t)B_ * LK_ * H_;
    short* Vt      = sp; sp += (size_t)B_ * H_ * LK_;   // [b][c][k]
    short* Qt      = sp; sp += (size_t)B_ * H_ * LQ_;   // [b][c][q]
    short* qctx    = sp; sp += (size_t)B_ * LQ_ * H_;
    short* vctx    = sp; sp += (size_t)B_ * LK_ * H_;
    short* WT      = sp; sp += 458752;
    short* WTo = WT + 262144;
    short* WT1 = WT + 327680;
    short* WT2 = WT + 393216;
    int* ip = (int*)(((size_t)sp + 15) & ~(size_t)15);
    int* head  = ip; ip += N_;          // 8192
    int* nxt   = ip; ip += B_ * LK_;    // 16384
    int* row2e = ip; ip += B_ * LK_;    // 16384
    float* fp = (float*)ip;
    float* obuf = fp; fp += (size_t)B_ * LQ_ * H_;   // f32 [8192,256]
    float* tbuf = fp; fp += (size_t)B_ * LK_ * H_;   // f32 [16384,256]

    phase1<<<10016, 256, 0, stream>>>(graph, rel, src, dst, eb, ep, pad_mask,
                                      Wq, Wk, Wv, Wo, W1, W2,
                                      WT, key_pad, val_pad, head, row2e, E);
    phase2_gemm<<<3072, 256, 0, stream>>>(query, key_pad, val_pad, WT,
                                          bq, bk, bv, Qb, Kb, Vt, Qt);
    phase3_attn<<<768, 512, 0, stream>>>(Qb, Kb, Vt, Qt, pad_mask, ext_mask,
                                         qctx, vctx);
    phase4a_gemm<<<1536, 256, 0, stream>>>(qctx, vctx, val_pad, WTo, WT1, WT2,
                                           obuf, tbuf);
    phase4b_ln<<<6144, 256, 0, stream>>>(obuf, bo, query, g1, be1, out_q,
                                         tbuf, vctx, val_pad, b1, b2, g2, be2,
                                         pad_mask, row2e, dst, head, nxt);
    finalize_graph<<<N_, 256, 0, stream>>>(head, nxt, tbuf, graph, out_g);
}

// Round 4
// 237.529 us; speedup vs baseline: 1.2287x; 1.0320x over previous
//
#include <hip/hip_runtime.h>
#include <hip/hip_bf16.h>
#include <string.h>

#define B_ 32
#define LQ_ 256
#define H_ 256
#define NH_ 8
#define LK_ 512
#define N_ 8192
#define DH_ 32

typedef float floatx4 __attribute__((ext_vector_type(4)));
typedef short shortx8 __attribute__((ext_vector_type(8)));
typedef short shortx4 __attribute__((ext_vector_type(4)));

__device__ __forceinline__ short f2b(float f) {
    __hip_bfloat16 h = __float2bfloat16(f);
    short s;
    __builtin_memcpy(&s, &h, 2);
    return s;
}
__device__ __forceinline__ float b2f(short s) {
    unsigned u = ((unsigned)(unsigned short)s) << 16;
    float f;
    __builtin_memcpy(&f, &u, 4);
    return f;
}

#define LOG2E 1.44269504088896f

// ================= PHASE 1: head/-row2e init ∥ prep_w ∥ gather =================
__global__ __launch_bounds__(256) void phase1(
    const float* __restrict__ graph, const float* __restrict__ rel,
    const int* __restrict__ src, const int* __restrict__ dst,
    const int* __restrict__ eb, const int* __restrict__ ep,
    const float* __restrict__ pad_mask,
    const float* __restrict__ Wq, const float* __restrict__ Wk,
    const float* __restrict__ Wv, const float* __restrict__ Wo,
    const float* __restrict__ W1, const float* __restrict__ W2,
    short* __restrict__ WT, short* __restrict__ key_pad,
    short* __restrict__ val_pad, int* __restrict__ head,
    int* __restrict__ row2e, int E) {
    const int bid = blockIdx.x, tid = threadIdx.x;
    if (bid < 8192) {
        int row = bid * 2 + (tid >> 7);
        int t = tid & 127;
        int b = row >> 9, p = row & 511;
        bool valid = pad_mask[row] > 0.5f;
        size_t krow = (size_t)row * 512;
        size_t vrow = (size_t)row * 256;
        int kc = t * 4, vc = t * 2;
        if (valid) {
            int lo = 0, hi = E;
            while (lo < hi) { int mid = (lo + hi) >> 1; if (eb[mid] < b) lo = mid + 1; else hi = mid; }
            int e = lo + p;
            int s = src[e], d = dst[e];
            const float* sp = (kc < 256) ? (graph + (size_t)s * 256 + kc)
                                         : (rel + (size_t)e * 256 + (kc - 256));
            float4 k4 = *(const float4*)sp;
            key_pad[krow + kc + 0] = f2b(k4.x);
            key_pad[krow + kc + 1] = f2b(k4.y);
            key_pad[krow + kc + 2] = f2b(k4.z);
            key_pad[krow + kc + 3] = f2b(k4.w);
            float2 v2 = *(const float2*)(graph + (size_t)d * 256 + vc);
            val_pad[vrow + vc + 0] = f2b(v2.x);
            val_pad[vrow + vc + 1] = f2b(v2.y);
        } else {
            *(long long*)&key_pad[krow + kc] = 0;
            *(int*)&val_pad[vrow + vc] = 0;
        }
    } else if (bid < 9984) {
        int i = (bid - 8192) * 256 + tid;
        const float* s;
        int K, loc;
        if (i < 65536) { s = Wq; K = 256; loc = i; }
        else if (i < 196608) { s = Wk; K = 512; loc = i - 65536; }
        else {
            int m = (i - 196608) >> 16;
            loc = (i - 196608) & 65535;
            K = 256;
            s = (m == 0) ? Wv : (m == 1) ? Wo : (m == 2) ? W1 : W2;
        }
        int n = loc / K, k = loc - n * K;
        WT[i] = f2b(s[(size_t)k * 256 + n]);
    } else {
        int i = (bid - 9984) * 256 + tid;   // 32 blocks -> 8192 threads
        if (i < 8192) head[i] = -1;
        for (int j = i; j < E; j += 8192)
            row2e[eb[j] * 512 + ep[j]] = j;
    }
}

// ========== PHASE 2: QKV GEMMs, 128x128 tiles (m97-style, 16 MFMA/wave/K-step) ==
// id<128: Qb = query@Wq ; 128..383: Kb = key_pad@Wk (K=512)
// 384..639: Vt[b][c][k] (A=WTv rows=c, B=val_pad rows=k)
// 640..767: Qt[b][c][q] (A=WTq rows=c, B=query f32 rows=q)
__global__ __launch_bounds__(256) void phase2_gemm(
    const float* __restrict__ query, const short* __restrict__ key_pad,
    const short* __restrict__ val_pad, const short* __restrict__ WT,
    const float* __restrict__ bq, const float* __restrict__ bk,
    const float* __restrict__ bv,
    short* __restrict__ Qb, short* __restrict__ Kb,
    short* __restrict__ Vt, short* __restrict__ Qt) {
    __shared__ short As[128][40];
    __shared__ short Bs[128][40];
    const int tid = threadIdx.x;
    const int id = blockIdx.x;
    const float* Af = nullptr; const short* Ab = nullptr;
    const float* Bf = nullptr; const short* Bb = nullptr;
    const float* bias; short* C;
    size_t cbase; int cstride, K; bool biasM;
    if (id < 128) {
        int mt = id >> 1, nt = id & 1;
        Af = query + (size_t)(mt * 128) * 256; K = 256;
        Bb = WT + (size_t)(nt * 128) * 256;
        bias = bq + nt * 128; biasM = false;
        C = Qb; cbase = (size_t)(mt * 128) * 256 + nt * 128; cstride = 256;
    } else if (id < 384) {
        int t = id - 128; int mt = t >> 1, nt = t & 1;
        Ab = key_pad + (size_t)(mt * 128) * 512; K = 512;
        Bb = WT + 65536 + (size_t)(nt * 128) * 512;
        bias = bk + nt * 128; biasM = false;
        C = Kb; cbase = (size_t)(mt * 128) * 256 + nt * 128; cstride = 256;
    } else if (id < 640) {
        int t = id - 384; int b = t >> 3, ct = (t >> 2) & 1, nt = t & 3;
        Ab = WT + 196608 + (size_t)(ct * 128) * 256; K = 256;
        Bb = val_pad + ((size_t)(b * 512 + nt * 128)) * 256;
        bias = bv + ct * 128; biasM = true;
        C = Vt; cbase = ((size_t)(b * 256 + ct * 128)) * 512 + nt * 128; cstride = 512;
    } else {
        int t = id - 640; int b = t >> 2, ct = (t >> 1) & 1, qt = t & 1;
        Ab = WT + (size_t)(ct * 128) * 256; K = 256;
        Bf = query + ((size_t)(b * 256 + qt * 128)) * 256;
        bias = bq + ct * 128; biasM = true;
        C = Qt; cbase = ((size_t)(b * 256 + ct * 128)) * 256 + qt * 128; cstride = 256;
    }
    const int w = tid >> 6, lane = tid & 63;
    const int R0 = (w >> 1) * 64, C0 = (w & 1) * 64;
    const int lm = lane & 15, quad = lane >> 4;
    const int sr = tid >> 1, skq = (tid & 1) * 16;

    floatx4 acc[4][4];
#pragma unroll
    for (int i = 0; i < 4; i++)
#pragma unroll
        for (int j = 0; j < 4; j++) acc[i][j] = {0.f, 0.f, 0.f, 0.f};

    for (int kc = 0; kc < K; kc += 32) {
        if (Af) {
            const float* ap = Af + (size_t)sr * K + kc + skq;
            float4 a1 = *(const float4*)ap, a2 = *(const float4*)(ap + 4);
            float4 a3 = *(const float4*)(ap + 8), a4 = *(const float4*)(ap + 12);
            As[sr][skq + 0] = f2b(a1.x); As[sr][skq + 1] = f2b(a1.y);
            As[sr][skq + 2] = f2b(a1.z); As[sr][skq + 3] = f2b(a1.w);
            As[sr][skq + 4] = f2b(a2.x); As[sr][skq + 5] = f2b(a2.y);
            As[sr][skq + 6] = f2b(a2.z); As[sr][skq + 7] = f2b(a2.w);
            As[sr][skq + 8] = f2b(a3.x); As[sr][skq + 9] = f2b(a3.y);
            As[sr][skq + 10] = f2b(a3.z); As[sr][skq + 11] = f2b(a3.w);
            As[sr][skq + 12] = f2b(a4.x); As[sr][skq + 13] = f2b(a4.y);
            As[sr][skq + 14] = f2b(a4.z); As[sr][skq + 15] = f2b(a4.w);
        } else {
            const short* ap = Ab + (size_t)sr * K + kc + skq;
            *(shortx8*)&As[sr][skq] = *(const shortx8*)ap;
            *(shortx8*)&As[sr][skq + 8] = *(const shortx8*)(ap + 8);
        }
        if (Bf) {
            const float* bp = Bf + (size_t)sr * K + kc + skq;
            float4 a1 = *(const float4*)bp, a2 = *(const float4*)(bp + 4);
            float4 a3 = *(const float4*)(bp + 8), a4 = *(const float4*)(bp + 12);
            Bs[sr][skq + 0] = f2b(a1.x); Bs[sr][skq + 1] = f2b(a1.y);
            Bs[sr][skq + 2] = f2b(a1.z); Bs[sr][skq + 3] = f2b(a1.w);
            Bs[sr][skq + 4] = f2b(a2.x); Bs[sr][skq + 5] = f2b(a2.y);
            Bs[sr][skq + 6] = f2b(a2.z); Bs[sr][skq + 7] = f2b(a2.w);
            Bs[sr][skq + 8] = f2b(a3.x); Bs[sr][skq + 9] = f2b(a3.y);
            Bs[sr][skq + 10] = f2b(a3.z); Bs[sr][skq + 11] = f2b(a3.w);
            Bs[sr][skq + 12] = f2b(a4.x); Bs[sr][skq + 13] = f2b(a4.y);
            Bs[sr][skq + 14] = f2b(a4.z); Bs[sr][skq + 15] = f2b(a4.w);
        } else {
            const short* bp = Bb + (size_t)sr * K + kc + skq;
            *(shortx8*)&Bs[sr][skq] = *(const shortx8*)bp;
            *(shortx8*)&Bs[sr][skq + 8] = *(const shortx8*)(bp + 8);
        }
        __syncthreads();
        shortx8 af[4], bf[4];
#pragma unroll
        for (int i = 0; i < 4; i++) {
            af[i] = *(const shortx8*)&As[R0 + i * 16 + lm][quad * 8];
            bf[i] = *(const shortx8*)&Bs[C0 + i * 16 + lm][quad * 8];
        }
#pragma unroll
        for (int i = 0; i < 4; i++)
#pragma unroll
            for (int j = 0; j < 4; j++)
                acc[i][j] = __builtin_amdgcn_mfma_f32_16x16x32_bf16(af[i], bf[j], acc[i][j], 0, 0, 0);
        __syncthreads();
    }
#pragma unroll
    for (int i = 0; i < 4; i++) {
#pragma unroll
        for (int j = 0; j < 4; j++) {
            int gn = C0 + j * 16 + lm;
#pragma unroll
            for (int r = 0; r < 4; r++) {
                int gm = R0 + i * 16 + quad * 4 + r;
                float bvv = biasM ? bias[gm] : bias[gn];
                C[cbase + (size_t)gm * cstride + gn] = f2b(acc[i][j][r] + bvv);
            }
        }
    }
}

// ================= PHASE 3: attention, (b,h)-blocked for exact reuse =========
__global__ __launch_bounds__(512, 4) void phase3_attn(
    const short* __restrict__ Qm, const short* __restrict__ Km,
    const short* __restrict__ Vt, const short* __restrict__ Qt,
    const float* __restrict__ pad_mask, const float* __restrict__ ext,
    short* __restrict__ qctx, short* __restrict__ vctx) {
    __shared__ short SA[128][40];    // K chunk [k][d] / Q chunk [q][d]
    __shared__ short ST[32][136];    // Vt slice [d][k] / Qt slice [d][q]
    __shared__ short P[8][32][72];   // wave-private P (row=out-idx, col=contraction)
    const int tid = threadIdx.x;
    const int w = tid >> 6, lane = tid & 63;
    const int lm = lane & 15, quad = lane >> 4;
    const float scale2 = 0.17677669529663687f * LOG2E;
    const int id = blockIdx.x;
    short (*Pw)[72] = P[w];

    if (id < 256) {
        const int b = id >> 3, h = id & 7;
        shortx8 bqf[2];
        bqf[0] = *(const shortx8*)(Qm + ((size_t)(b * 256 + w * 32 + lm)) * 256 + h * 32 + quad * 8);
        bqf[1] = *(const shortx8*)(Qm + ((size_t)(b * 256 + w * 32 + 16 + lm)) * 256 + h * 32 + quad * 8);
        floatx4 oacc[2][2] = {{{0.f,0.f,0.f,0.f},{0.f,0.f,0.f,0.f}},
                              {{0.f,0.f,0.f,0.f},{0.f,0.f,0.f,0.f}}};
        float psum[2] = {0.f, 0.f};
        const floatx4* pmp = (const floatx4*)(pad_mask + b * 512);
        for (int kc = 0; kc < 512; kc += 128) {
            if (tid < 256) {          // K chunk [128][32]
                int r = tid >> 1, dq = (tid & 1) * 16;
                const short* kp = Km + ((size_t)(b * 512 + kc + r)) * 256 + h * 32 + dq;
                *(shortx8*)&SA[r][dq] = *(const shortx8*)kp;
                *(shortx8*)&SA[r][dq + 8] = *(const shortx8*)(kp + 8);
            } else {                  // Vt slice [32][128]
                int u = tid - 256;
                int r = u >> 3, kq = (u & 7) * 16;
                const short* vp = Vt + ((size_t)(b * 256 + h * 32 + r)) * 512 + kc + kq;
                *(shortx8*)&ST[r][kq] = *(const shortx8*)vp;
                *(shortx8*)&ST[r][kq + 8] = *(const shortx8*)(vp + 8);
            }
            __syncthreads();
#pragma unroll
            for (int kh = 0; kh < 2; kh++) {
#pragma unroll
                for (int kt = 0; kt < 4; kt++) {
                    shortx8 ak = *(const shortx8*)&SA[kh * 64 + kt * 16 + lm][quad * 8];
                    floatx4 pm = pmp[kc / 4 + kh * 16 + kt * 4 + quad];
#pragma unroll
                    for (int qf = 0; qf < 2; qf++) {
                        floatx4 s = {0.f, 0.f, 0.f, 0.f};
                        s = __builtin_amdgcn_mfma_f32_16x16x32_bf16(ak, bqf[qf], s, 0, 0, 0);
                        shortx4 p4;
#pragma unroll
                        for (int r = 0; r < 4; r++) {
                            float e = __builtin_amdgcn_exp2f(
                                s[r] * scale2 + (1.0f - pm[r]) * (-10000.0f * LOG2E));
                            psum[qf] += e;
                            p4[r] = f2b(e);
                        }
                        *(long long*)&Pw[qf * 16 + lm][kt * 16 + quad * 4] = *(long long*)&p4;
                    }
                }
#pragma unroll
                for (int ks = 0; ks < 2; ks++) {
#pragma unroll
                    for (int qf = 0; qf < 2; qf++) {
                        shortx8 pb = *(const shortx8*)&Pw[qf * 16 + lm][ks * 32 + quad * 8];
#pragma unroll
                        for (int di = 0; di < 2; di++) {
                            shortx8 av = *(const shortx8*)&ST[di * 16 + lm][kh * 64 + ks * 32 + quad * 8];
                            oacc[qf][di] = __builtin_amdgcn_mfma_f32_16x16x32_bf16(av, pb, oacc[qf][di], 0, 0, 0);
                        }
                    }
                }
            }
            __syncthreads();
        }
#pragma unroll
        for (int qf = 0; qf < 2; qf++) {
            psum[qf] += __shfl_xor(psum[qf], 16, 64);
            psum[qf] += __shfl_xor(psum[qf], 32, 64);
            float inv = 1.0f / psum[qf];
            int q = w * 32 + qf * 16 + lm;
            short* op = qctx + ((size_t)(b * 256 + q)) * 256 + h * 32;
#pragma unroll
            for (int di = 0; di < 2; di++) {
                shortx4 o;
#pragma unroll
                for (int r = 0; r < 4; r++) o[r] = f2b(oacc[qf][di][r] * inv);
                *(long long*)(op + di * 16 + quad * 4) = *(long long*)&o;
            }
        }
    } else {
        const int t = id - 256;
        const int b = t >> 4, h = (t >> 1) & 7, khb = t & 1;
        shortx8 bkf[2];
        bkf[0] = *(const shortx8*)(Km + ((size_t)(b * 512 + khb * 256 + w * 32 + lm)) * 256 + h * 32 + quad * 8);
        bkf[1] = *(const shortx8*)(Km + ((size_t)(b * 512 + khb * 256 + w * 32 + 16 + lm)) * 256 + h * 32 + quad * 8);
        floatx4 oacc[2][2] = {{{0.f,0.f,0.f,0.f},{0.f,0.f,0.f,0.f}},
                              {{0.f,0.f,0.f,0.f},{0.f,0.f,0.f,0.f}}};
        float psum[2] = {0.f, 0.f};
        const floatx4* emp = (const floatx4*)(ext + b * 256);
        for (int qc = 0; qc < 256; qc += 128) {
            if (tid < 256) {          // Q chunk [128][32]
                int r = tid >> 1, dq = (tid & 1) * 16;
                const short* qp = Qm + ((size_t)(b * 256 + qc + r)) * 256 + h * 32 + dq;
                *(shortx8*)&SA[r][dq] = *(const shortx8*)qp;
                *(shortx8*)&SA[r][dq + 8] = *(const shortx8*)(qp + 8);
            } else {                  // Qt slice [32][128]
                int u = tid - 256;
                int r = u >> 3, kq = (u & 7) * 16;
                const short* tp = Qt + ((size_t)(b * 256 + h * 32 + r)) * 256 + qc + kq;
                *(shortx8*)&ST[r][kq] = *(const shortx8*)tp;
                *(shortx8*)&ST[r][kq + 8] = *(const shortx8*)(tp + 8);
            }
            __syncthreads();
#pragma unroll
            for (int qh = 0; qh < 2; qh++) {
#pragma unroll
                for (int qt = 0; qt < 4; qt++) {
                    shortx8 aq = *(const shortx8*)&SA[qh * 64 + qt * 16 + lm][quad * 8];
                    floatx4 em = emp[qc / 4 + qh * 16 + qt * 4 + quad];
#pragma unroll
                    for (int kf = 0; kf < 2; kf++) {
                        floatx4 s = {0.f, 0.f, 0.f, 0.f};
                        s = __builtin_amdgcn_mfma_f32_16x16x32_bf16(aq, bkf[kf], s, 0, 0, 0);
                        shortx4 p4;
#pragma unroll
                        for (int r = 0; r < 4; r++) {
                            float e = __builtin_amdgcn_exp2f(s[r] * scale2 + em[r] * LOG2E);
                            psum[kf] += e;
                            p4[r] = f2b(e);
                        }
                        *(long long*)&Pw[kf * 16 + lm][qt * 16 + quad * 4] = *(long long*)&p4;
                    }
                }
#pragma unroll
                for (int ks = 0; ks < 2; ks++) {
#pragma unroll
                    for (int kf = 0; kf < 2; kf++) {
                        shortx8 pb = *(const shortx8*)&Pw[kf * 16 + lm][ks * 32 + quad * 8];
#pragma unroll
                        for (int di = 0; di < 2; di++) {
                            shortx8 aT = *(const shortx8*)&ST[di * 16 + lm][qh * 64 + ks * 32 + quad * 8];
                            oacc[kf][di] = __builtin_amdgcn_mfma_f32_16x16x32_bf16(aT, pb, oacc[kf][di], 0, 0, 0);
                        }
                    }
                }
            }
            __syncthreads();
        }
#pragma unroll
        for (int kf = 0; kf < 2; kf++) {
            psum[kf] += __shfl_xor(psum[kf], 16, 64);
            psum[kf] += __shfl_xor(psum[kf], 32, 64);
            float inv = 1.0f / psum[kf];
            int k = khb * 256 + w * 32 + kf * 16 + lm;
            short* op = vctx + ((size_t)(b * 512 + k)) * 256 + h * 32;
#pragma unroll
            for (int di = 0; di < 2; di++) {
                shortx4 o;
#pragma unroll
                for (int r = 0; r < 4; r++) o[r] = f2b(oacc[kf][di][r] * inv);
                *(long long*)(op + di * 16 + quad * 4) = *(long long*)&o;
            }
        }
    }
}

// ========== PHASE 4a: tail GEMMs, 128x128 tiles, f32 out ==========
// id<128: obuf = qctx@WTo ; 128..383: tbuf = vctx@WT1 + val_pad@WT2
__global__ __launch_bounds__(256) void phase4a_gemm(
    const short* __restrict__ qctx, const short* __restrict__ vctx,
    const short* __restrict__ val_pad, const short* __restrict__ WTo,
    const short* __restrict__ WT1, const short* __restrict__ WT2,
    float* __restrict__ obuf, float* __restrict__ tbuf) {
    __shared__ short As[128][40];
    __shared__ short Bs[128][40];
    const int tid = threadIdx.x;
    const int id = blockIdx.x;
    const bool is_out = id < 128;
    int t = is_out ? id : id - 128;
    const int mt = t >> 1, nt = t & 1;
    const int w = tid >> 6, lane = tid & 63;
    const int R0 = (w >> 1) * 64, C0 = (w & 1) * 64;
    const int lm = lane & 15, quad = lane >> 4;
    const int sr = tid >> 1, skq = (tid & 1) * 16;
    const int npair = is_out ? 1 : 2;

    floatx4 acc[4][4];
#pragma unroll
    for (int i = 0; i < 4; i++)
#pragma unroll
        for (int j = 0; j < 4; j++) acc[i][j] = {0.f, 0.f, 0.f, 0.f};

    for (int pair = 0; pair < npair; pair++) {
        const short* Ap = is_out ? (qctx + (size_t)(mt * 128) * 256)
                                 : (pair == 0 ? vctx + (size_t)(mt * 128) * 256
                                              : val_pad + (size_t)(mt * 128) * 256);
        const short* Bp = is_out ? (WTo + (size_t)(nt * 128) * 256)
                                 : (pair == 0 ? WT1 + (size_t)(nt * 128) * 256
                                              : WT2 + (size_t)(nt * 128) * 256);
        for (int kc = 0; kc < 256; kc += 32) {
            const short* ap = Ap + (size_t)sr * 256 + kc + skq;
            *(shortx8*)&As[sr][skq] = *(const shortx8*)ap;
            *(shortx8*)&As[sr][skq + 8] = *(const shortx8*)(ap + 8);
            const short* bp = Bp + (size_t)sr * 256 + kc + skq;
            *(shortx8*)&Bs[sr][skq] = *(const shortx8*)bp;
            *(shortx8*)&Bs[sr][skq + 8] = *(const shortx8*)(bp + 8);
            __syncthreads();
            shortx8 af[4], bf[4];
#pragma unroll
            for (int i = 0; i < 4; i++) {
                af[i] = *(const shortx8*)&As[R0 + i * 16 + lm][quad * 8];
                bf[i] = *(const shortx8*)&Bs[C0 + i * 16 + lm][quad * 8];
            }
#pragma unroll
            for (int i = 0; i < 4; i++)
#pragma unroll
                for (int j = 0; j < 4; j++)
                    acc[i][j] = __builtin_amdgcn_mfma_f32_16x16x32_bf16(af[i], bf[j], acc[i][j], 0, 0, 0);
            __syncthreads();
        }
    }
    float* C = is_out ? obuf : tbuf;
    const size_t cbase = (size_t)(mt * 128) * 256 + nt * 128;
#pragma unroll
    for (int i = 0; i < 4; i++) {
#pragma unroll
        for (int j = 0; j < 4; j++) {
            int gn = C0 + j * 16 + lm;
#pragma unroll
            for (int r = 0; r < 4; r++) {
                int gm = R0 + i * 16 + quad * 4 + r;
                C[cbase + (size_t)gm * 256 + gn] = acc[i][j][r];
            }
        }
    }
}

// ===== PHASE 4b: LN epilogues (1 row / wave); gate writes y in-place into tbuf
//       and pushes its row onto a per-dst lock-free list (1 atomicExch / row) ====
__global__ __launch_bounds__(256) void phase4b_ln(
    const float* __restrict__ obuf, const float* __restrict__ bo,
    const float* __restrict__ query, const float* __restrict__ g1,
    const float* __restrict__ be1, float* __restrict__ out_q,
    float* __restrict__ tbuf, const short* __restrict__ vctx,
    const short* __restrict__ val_pad, const float* __restrict__ b1_,
    const float* __restrict__ b2_, const float* __restrict__ g2,
    const float* __restrict__ be2, const float* __restrict__ pad_mask,
    const int* __restrict__ row2e, const int* __restrict__ dst,
    int* __restrict__ head, int* __restrict__ nxt) {
    const int lane = threadIdx.x & 63, w = threadIdx.x >> 6;
    const int c0 = lane * 4;
    if (blockIdx.x < 2048) {
        int row = blockIdx.x * 4 + w;
        long long base = (long long)row * H_ + c0;
        float4 o = *(const float4*)(obuf + base);
        float4 bo4 = *(const float4*)(bo + c0);
        float4 q4 = *(const float4*)(query + base);
        float x0 = o.x + bo4.x + q4.x, x1 = o.y + bo4.y + q4.y;
        float x2 = o.z + bo4.z + q4.z, x3 = o.w + bo4.w + q4.w;
        float t = x0 + x1 + x2 + x3;
        for (int off = 32; off > 0; off >>= 1) t += __shfl_xor(t, off, 64);
        float mean = t * (1.0f / H_);
        float d0 = x0 - mean, d1 = x1 - mean, d2 = x2 - mean, d3 = x3 - mean;
        float v = d0 * d0 + d1 * d1 + d2 * d2 + d3 * d3;
        for (int off = 32; off > 0; off >>= 1) v += __shfl_xor(v, off, 64);
        float rs = rsqrtf(v * (1.0f / H_) + 1e-12f);
        float4 g = *(const float4*)(g1 + c0);
        float4 be = *(const float4*)(be1 + c0);
        float4 out;
        out.x = d0 * rs * g.x + be.x; out.y = d1 * rs * g.y + be.y;
        out.z = d2 * rs * g.z + be.z; out.w = d3 * rs * g.w + be.w;
        *(float4*)(out_q + base) = out;
    } else {
        int row = (blockIdx.x - 2048) * 4 + w;
        if (pad_mask[row] > 0.5f) {
            long long base = (long long)row * H_ + c0;
            float4 tb = *(const float4*)(tbuf + base);
            float4 b14 = *(const float4*)(b1_ + c0);
            float4 b24 = *(const float4*)(b2_ + c0);
            shortx4 vc = *(const shortx4*)(vctx + base);
            shortx4 vp = *(const shortx4*)(val_pad + base);
            float x[4];
#pragma unroll
            for (int j = 0; j < 4; j++) {
                float tv = (j == 0) ? tb.x : (j == 1) ? tb.y : (j == 2) ? tb.z : tb.w;
                float bb1 = (j == 0) ? b14.x : (j == 1) ? b14.y : (j == 2) ? b14.z : b14.w;
                float bb2 = (j == 0) ? b24.x : (j == 1) ? b24.y : (j == 2) ? b24.z : b24.w;
                float th = 1.0f / (1.0f + __expf(-(tv + bb1 + bb2)));
                x[j] = th * b2f(vc[j]) + (1.0f - th) * b2f(vp[j]);
            }
            float t = x[0] + x[1] + x[2] + x[3];
            for (int off = 32; off > 0; off >>= 1) t += __shfl_xor(t, off, 64);
            float mean = t * (1.0f / H_);
            float d0 = x[0] - mean, d1 = x[1] - mean, d2 = x[2] - mean, d3 = x[3] - mean;
            float v = d0 * d0 + d1 * d1 + d2 * d2 + d3 * d3;
            for (int off = 32; off > 0; off >>= 1) v += __shfl_xor(v, off, 64);
            float rs = rsqrtf(v * (1.0f / H_) + 1e-12f);
            float4 g = *(const float4*)(g2 + c0);
            float4 be = *(const float4*)(be2 + c0);
            float4 y4;
            y4.x = d0 * rs * g.x + be.x; y4.y = d1 * rs * g.y + be.y;
            y4.z = d2 * rs * g.z + be.z; y4.w = d3 * rs * g.w + be.w;
            *(float4*)(tbuf + base) = y4;   // in-place: same addresses just read
            if (lane == 0) {
                int d = dst[row2e[row]];
                int prev = atomicExch(&head[d], row);
                nxt[row] = prev;
            }
        }
    }
}

// ================= PHASE 5: finalize (walk per-node edge list) =================
__global__ __launch_bounds__(256) void finalize_graph(
    const int* __restrict__ head, const int* __restrict__ nxt,
    const float* __restrict__ yrows, const float* __restrict__ graph,
    float* __restrict__ out_g) {
    int n = blockIdx.x, c = threadIdx.x;
    long long idx = (long long)n * H_ + c;
    int e = head[n];
    if (e < 0) { out_g[idx] = graph[idx]; return; }
    float acc = 0.f;
    int cnt = 0;
    while (e >= 0) {
        acc += yrows[(size_t)e * H_ + c];
        cnt++;
        e = nxt[e];
    }
    out_g[idx] = acc / (float)cnt;
}

extern "C" void kernel_launch(void* const* d_in, const int* in_sizes, int n_in,
                              void* d_out, int out_size, void* d_ws, size_t ws_size,
                              hipStream_t stream) {
    const float* ext_mask = (const float*)d_in[0];
    const float* query    = (const float*)d_in[1];
    const float* rel      = (const float*)d_in[2];
    const float* graph    = (const float*)d_in[3];
    const int*  src      = (const int*)d_in[4];
    const int*  dst      = (const int*)d_in[5];
    const int*  eb       = (const int*)d_in[6];
    const int*  ep       = (const int*)d_in[7];
    const float* pad_mask = (const float*)d_in[8];
    const float* Wq = (const float*)d_in[9];  const float* bq = (const float*)d_in[10];
    const float* Wk = (const float*)d_in[11]; const float* bk = (const float*)d_in[12];
    const float* Wv = (const float*)d_in[13]; const float* bv = (const float*)d_in[14];
    const float* Wo = (const float*)d_in[15]; const float* bo = (const float*)d_in[16];
    const float* g1 = (const float*)d_in[17]; const float* be1 = (const float*)d_in[18];
    const float* W1 = (const float*)d_in[19]; const float* b1 = (const float*)d_in[20];
    const float* W2 = (const float*)d_in[21]; const float* b2 = (const float*)d_in[22];
    const float* g2 = (const float*)d_in[23]; const float* be2 = (const float*)d_in[24];
    const int E = in_sizes[2] / H_;

    float* out_g = (float*)d_out;
    float* out_q = (float*)d_out + (size_t)N_ * H_;

    short* sp = (short*)d_ws;
    short* key_pad = sp; sp += (size_t)B_ * LK_ * 2 * H_;
    short* val_pad = sp; sp += (size_t)B_ * LK_ * H_;
    short* Qb      = sp; sp += (size_t)B_ * LQ_ * H_;
    short* Kb      = sp; sp += (size_t)B_ * LK_ * H_;
    short* Vt      = sp; sp += (size_t)B_ * H_ * LK_;   // [b][c][k]
    short* Qt      = sp; sp += (size_t)B_ * H_ * LQ_;   // [b][c][q]
    short* qctx    = sp; sp += (size_t)B_ * LQ_ * H_;
    short* vctx    = sp; sp += (size_t)B_ * LK_ * H_;
    short* WT      = sp; sp += 458752;
    short* WTo = WT + 262144;
    short* WT1 = WT + 327680;
    short* WT2 = WT + 393216;
    int* ip = (int*)(((size_t)sp + 15) & ~(size_t)15);
    int* head  = ip; ip += N_;          // 8192
    int* nxt   = ip; ip += B_ * LK_;    // 16384
    int* row2e = ip; ip += B_ * LK_;    // 16384
    float* fp = (float*)ip;
    float* obuf = fp; fp += (size_t)B_ * LQ_ * H_;   // f32 [8192,256]
    float* tbuf = fp; fp += (size_t)B_ * LK_ * H_;   // f32 [16384,256]

    phase1<<<10016, 256, 0, stream>>>(graph, rel, src, dst, eb, ep, pad_mask,
                                      Wq, Wk, Wv, Wo, W1, W2,
                                      WT, key_pad, val_pad, head, row2e, E);
    phase2_gemm<<<768, 256, 0, stream>>>(query, key_pad, val_pad, WT,
                                         bq, bk, bv, Qb, Kb, Vt, Qt);
    phase3_attn<<<768, 512, 0, stream>>>(Qb, Kb, Vt, Qt, pad_mask, ext_mask,
                                         qctx, vctx);
    phase4a_gemm<<<384, 256, 0, stream>>>(qctx, vctx, val_pad, WTo, WT1, WT2,
                                          obuf, tbuf);
    phase4b_ln<<<6144, 256, 0, stream>>>(obuf, bo, query, g1, be1, out_q,
                                         tbuf, vctx, val_pad, b1, b2, g2, be2,
                                         pad_mask, row2e, dst, head, nxt);
    finalize_graph<<<N_, 256, 0, stream>>>(head, nxt, tbuf, graph, out_g);
}